// Round 3
// baseline (4577.227 us; speedup 1.0000x reference)
//
#include <hip/hip_runtime.h>
#include <math.h>

#define HH 376
#define WW 376
#define HWSZ (HH*WW)          // 141376
#define NSC (3*HWSZ)          // 424128
#define KTOP 500
#define CAND_CAP 65536
#define SORT_M 4096
#define NBIN 65536

// conv64v2 tiling: 64x8 pixel tile, thread = 2 cols x 8 rows x 8 ocs
#define ICB2 8
#define C_SINW 68             // 66 used (64 body + 2 halo), padded to 68
#define C_SINH 10

// head tiling (round-2 kernel, unchanged)
#define HTW 32
#define H_SINW 34
#define HICB 2
#define HTH 64
#define H_SINH 66
#define H_NLOAD (HICB*H_SINH*H_SINW) // 4488
#define H_NPF ((H_NLOAD+255)/256)    // 18

// ---------------------------------------------------------------------------
// Weight reorder -> [b][chunk][icl][OC=64][12] (9 real + 3 zero pad) so each
// oc row is 48B (16B-aligned) for ds_read_b128, and per-chunk staging is a
// contiguous float4 copy.
// ---------------------------------------------------------------------------
__global__ void reorder_w12_kernel(const float* __restrict__ src, float* __restrict__ dst,
                                   int IC, int total)
{
    int i = blockIdx.x*256 + threadIdx.x;
    if (i >= total) return;
    int per = IC*64*12;
    int b  = i / per;
    int r  = i - b*per;
    int chunk = r / (ICB2*64*12);
    int r2 = r - chunk*(ICB2*64*12);
    int icl = r2 / (64*12);
    int r3  = r2 - icl*(64*12);
    int oc  = r3 / 12;
    int k   = r3 - oc*12;
    float v = 0.f;
    if (k < 9) {
        int ic = chunk*ICB2 + icl;
        v = src[(size_t)b*64*IC*9 + ((size_t)oc*IC + ic)*9 + k];
    }
    dst[i] = v;
}

// old-style reorder for the head kernel: [b][chunk][icl][3][9]
__global__ void reorder_w_kernel(const float* __restrict__ src, float* __restrict__ dst,
                                 int IC, int ICB, int OC, int total)
{
    int i = blockIdx.x*256 + threadIdx.x;
    if (i >= total) return;
    int per = OC*IC*9;
    int b = i / per;
    int j = i - b*per;
    int chunksz = ICB*OC*9;
    int chunk = j / chunksz;
    int r = j - chunk*chunksz;
    int icl = r / (OC*9);
    int rr = r - icl*(OC*9);
    int oc = rr / 9;
    int kk = rr - oc*9;
    int ic = chunk*ICB + icl;
    dst[i] = src[b*per + (oc*IC + ic)*9 + kk];
}

// ---------------------------------------------------------------------------
// conv64v2: 3x3 SAME conv, IC -> 64 oc, BN+ReLU. Tile 64x8, block 256.
// Thread = 2 adjacent cols x 8 rows x 8 ocs (128 acc). LDS reads are
// vectorized: vin = 20x ds_read_b64 / ic, weights = 24x ds_read_b128 / ic.
// Accumulation order per output is IDENTICAL to round-2 (ic asc, w0..w8
// fmaf chain) - required for bit-stable top-k ordering.
// ---------------------------------------------------------------------------
template<int IC>
__global__ __launch_bounds__(256,2) void conv64v2_kernel(
    const float* __restrict__ in,    // [IC][H][W]
    const float* __restrict__ rw,    // [IC/8][8][64][12] reordered+padded
    const float* __restrict__ bnp,   // [4][64]
    float* __restrict__ out)         // [64][H][W]
{
    __shared__ float s_in[ICB2][C_SINH][C_SINW];
    __shared__ float s_w[ICB2][64][12];

    const int tid  = threadIdx.x;
    const int x0   = blockIdx.x * 64;
    const int y0   = blockIdx.y * 8;
    const int lx   = tid & 31;          // col pair (2lx, 2lx+1)
    const int slot = tid >> 5;          // oc group: slot*8 .. slot*8+7

    float acc[8][16];                   // [o][j*2+col]
#pragma unroll
    for (int o = 0; o < 8; o++)
#pragma unroll
        for (int jc = 0; jc < 16; jc++) acc[o][jc] = 0.f;

    // ---- body prefetch: 5 float4 per thread per chunk (exactly 1280 f4) ----
    // idx = tid + 256k over [ic][r][c4]: ic=idx/160, r=(idx%160)/16, c4=idx&15
    const float* bptr[5];
    bool bval[5];
    int bsidx[5];
#pragma unroll
    for (int k = 0; k < 5; k++) {
        int idx = tid + k*256;
        int ic  = idx / 160;
        int rem = idx - ic*160;
        int r   = rem >> 4;
        int c4  = rem & 15;
        int gy  = y0 + r - 1;
        int gx  = x0 + 4*c4;            // 4 cols gx..gx+3, all valid or all OOB
        bval[k] = (gy >= 0) && (gy < HH) && (gx + 3 < WW);
        bptr[k] = in + ((long)ic*HWSZ + (long)gy*WW + gx);
        bsidx[k]= ic*(C_SINH*C_SINW) + r*C_SINW + 1 + 4*c4;
    }
    // ---- halo prefetch: 160 elements, threads 0..159 ----
    const float* hptr = in;
    bool hval = false;
    int hsidx = 0;
    if (tid < 160) {
        int side = tid & 1;
        int e    = tid >> 1;            // 0..79
        int ic   = e / 10;
        int r    = e - ic*10;
        int gy   = y0 + r - 1;
        int gx   = side ? (x0 + 64) : (x0 - 1);
        hval  = (gy >= 0) && (gy < HH) && (gx >= 0) && (gx < WW);
        hptr  = in + ((long)ic*HWSZ + (long)gy*WW + gx);
        hsidx = ic*(C_SINH*C_SINW) + r*C_SINW + (side ? 65 : 0);
    }

    float4 pf[5];
    float hpf = 0.f;
    auto do_prefetch = [&]() {
#pragma unroll
        for (int k = 0; k < 5; k++) {
            pf[k] = bval[k] ? *(const float4*)bptr[k] : float4{0.f,0.f,0.f,0.f};
            bptr[k] += (long)ICB2*HWSZ;
        }
        hpf = hval ? hptr[0] : 0.f;
        hptr += (long)ICB2*HWSZ;
    };
    do_prefetch();

    float* s_in_flat = &s_in[0][0][0];

    for (int ic0 = 0; ic0 < IC; ic0 += ICB2) {
        __syncthreads();                       // previous compute done
        // store prefetched body + halo
#pragma unroll
        for (int k = 0; k < 5; k++) {
            s_in_flat[bsidx[k]+0] = pf[k].x;
            s_in_flat[bsidx[k]+1] = pf[k].y;
            s_in_flat[bsidx[k]+2] = pf[k].z;
            s_in_flat[bsidx[k]+3] = pf[k].w;
        }
        if (tid < 160) s_in_flat[hsidx] = hpf;
        // stage weights: contiguous 6144 floats = 1536 f4, 6 per thread
        {
            const float4* wsrc = (const float4*)(rw + (size_t)(ic0/ICB2)*(ICB2*64*12));
            float4* wdst = (float4*)&s_w[0][0][0];
#pragma unroll
            for (int k = 0; k < 6; k++)
                wdst[tid + k*256] = wsrc[tid + k*256];
        }
        __syncthreads();
        if (ic0 + ICB2 < IC) do_prefetch();    // overlap next chunk's loads

#pragma unroll 1
        for (int ic = 0; ic < ICB2; ic++) {
            float vin[C_SINH][4];
#pragma unroll
            for (int r = 0; r < C_SINH; r++) {
                float2 a = *(const float2*)&s_in[ic][r][2*lx];
                float2 b = *(const float2*)&s_in[ic][r][2*lx+2];
                vin[r][0] = a.x; vin[r][1] = a.y; vin[r][2] = b.x; vin[r][3] = b.y;
            }
#pragma unroll
            for (int o = 0; o < 8; o++) {
                const float* wp = &s_w[ic][slot*8+o][0];
                float w0=wp[0],w1=wp[1],w2=wp[2],w3=wp[3],w4=wp[4],
                      w5=wp[5],w6=wp[6],w7=wp[7],w8=wp[8];
#pragma unroll
                for (int j = 0; j < 8; j++) {
#pragma unroll
                    for (int c = 0; c < 2; c++) {
                        float s = acc[o][j*2+c];
                        s = fmaf(w0, vin[j  ][c  ], s);
                        s = fmaf(w1, vin[j  ][c+1], s);
                        s = fmaf(w2, vin[j  ][c+2], s);
                        s = fmaf(w3, vin[j+1][c  ], s);
                        s = fmaf(w4, vin[j+1][c+1], s);
                        s = fmaf(w5, vin[j+1][c+2], s);
                        s = fmaf(w6, vin[j+2][c  ], s);
                        s = fmaf(w7, vin[j+2][c+1], s);
                        s = fmaf(w8, vin[j+2][c+2], s);
                        acc[o][j*2+c] = s;
                    }
                }
            }
        }
    }

    // ---- epilogue: BN + ReLU, float2 stores (pairs never straddle W=376) ----
    const int gx = x0 + 2*lx;
    if (gx < WW) {
#pragma unroll
        for (int o = 0; o < 8; o++) {
            int oc = slot*8 + o;
            float g = bnp[oc], b = bnp[64+oc], m = bnp[128+oc], v = bnp[192+oc];
            float sc = g * rsqrtf(v + 1e-5f);
            float sh = b - m * sc;
#pragma unroll
            for (int j = 0; j < 8; j++) {
                float2 val;
                val.x = fmaxf(fmaf(acc[o][j*2+0], sc, sh), 0.f);
                val.y = fmaxf(fmaf(acc[o][j*2+1], sc, sh), 0.f);
                *(float2*)&out[(size_t)oc*HWSZ + (size_t)(y0+j)*WW + gx] = val;
            }
        }
    }
}

// ---------------------------------------------------------------------------
// head: 3x3 conv 64 -> nch (<=3) + bias (round-2 kernel, verified).
// ---------------------------------------------------------------------------
__global__ __launch_bounds__(256,3) void head_kernel(
    const float* __restrict__ in,    // [64][H][W]
    const float* __restrict__ rw,    // reordered [32][2][3][9]
    const float* __restrict__ bias,  // [3]
    float* __restrict__ out,         // [nch][H][W]
    int nch)
{
    __shared__ float s_in[HICB][H_SINH][H_SINW];
    __shared__ float s_w[HICB][3][9];

    const int tid  = threadIdx.x;
    const int x0   = blockIdx.x * HTW;
    const int y0   = blockIdx.y * HTH;
    const int lx   = tid & 31;
    const int slot = tid >> 5;          // row octet

    float acc[3][8];
#pragma unroll
    for (int o = 0; o < 3; o++)
#pragma unroll
        for (int j = 0; j < 8; j++) acc[o][j] = 0.f;

    const float* pfp[H_NPF];
    bool pfv[H_NPF];
#pragma unroll
    for (int k = 0; k < H_NPF; k++) {
        int idx = tid + k*256;
        int ic  = idx / (H_SINH*H_SINW);
        int rem = idx - ic*(H_SINH*H_SINW);
        int r   = rem / H_SINW;
        int c   = rem - r*H_SINW;
        int gy  = y0 + r - 1;
        int gx  = x0 + c - 1;
        pfv[k] = (idx < H_NLOAD) && gy >= 0 && gy < HH && gx >= 0 && gx < WW;
        pfp[k] = in + ((long)ic*HWSZ + (long)gy*WW + gx);
    }
    float pf[H_NPF];
    auto do_prefetch = [&]() {
#pragma unroll
        for (int k = 0; k < H_NPF; k++) {
            pf[k] = pfv[k] ? pfp[k][0] : 0.f;
            pfp[k] += (long)HICB*HWSZ;
        }
    };
    do_prefetch();

    for (int ic0 = 0; ic0 < 64; ic0 += HICB) {
        __syncthreads();
#pragma unroll
        for (int k = 0; k < H_NPF; k++) {
            int idx = tid + k*256;
            if (idx < H_NLOAD) (&s_in[0][0][0])[idx] = pf[k];
        }
        if (tid < HICB*3*9)
            (&s_w[0][0][0])[tid] = rw[(size_t)(ic0/HICB)*(HICB*3*9) + tid];
        __syncthreads();
        if (ic0 + HICB < 64) do_prefetch();

#pragma unroll 1
        for (int ic = 0; ic < HICB; ic++) {
            float vin[10][3];
#pragma unroll
            for (int r = 0; r < 10; r++) {
                vin[r][0] = s_in[ic][slot*8 + r][lx];
                vin[r][1] = s_in[ic][slot*8 + r][lx+1];
                vin[r][2] = s_in[ic][slot*8 + r][lx+2];
            }
#pragma unroll
            for (int o = 0; o < 3; o++) {
                const float* wp = &s_w[ic][o][0];
                float w0=wp[0],w1=wp[1],w2=wp[2],w3=wp[3],w4=wp[4],
                      w5=wp[5],w6=wp[6],w7=wp[7],w8=wp[8];
#pragma unroll
                for (int j = 0; j < 8; j++) {
                    float s = acc[o][j];
                    s = fmaf(w0, vin[j  ][0], s);
                    s = fmaf(w1, vin[j  ][1], s);
                    s = fmaf(w2, vin[j  ][2], s);
                    s = fmaf(w3, vin[j+1][0], s);
                    s = fmaf(w4, vin[j+1][1], s);
                    s = fmaf(w5, vin[j+1][2], s);
                    s = fmaf(w6, vin[j+2][0], s);
                    s = fmaf(w7, vin[j+2][1], s);
                    s = fmaf(w8, vin[j+2][2], s);
                    acc[o][j] = s;
                }
            }
        }
    }

    const int gx = x0 + lx;
    if (gx < WW) {
#pragma unroll
        for (int o = 0; o < 3; o++) {
            if (o < nch) {
                float bo = bias[o];
#pragma unroll
                for (int j = 0; j < 8; j++) {
                    int gy = y0 + slot*8 + j;
                    if (gy < HH)
                        out[(size_t)o*HWSZ + (size_t)gy*WW + gx] = acc[o][j] + bo;
                }
            }
        }
    }
}

// ---------------------------------------------------------------------------
// Top-K machinery (verified correct, unchanged).
// ---------------------------------------------------------------------------
__global__ void hist_kernel(const float* __restrict__ hm, unsigned* __restrict__ hist)
{
    int i = blockIdx.x * 256 + threadIdx.x;
    if (i < NSC) {
        float sc = 1.f / (1.f + expf(-hm[i]));
        unsigned key = __float_as_uint(sc);
        atomicAdd(&hist[key >> 16], 1u);
    }
}

__global__ void scan_kernel(const unsigned* __restrict__ hist, unsigned* __restrict__ meta)
{
    __shared__ unsigned part[1024];
    __shared__ unsigned suf[1024];
    const int t = threadIdx.x;
    unsigned ssum = 0;
    for (int b = t*64; b < t*64 + 64; b++) ssum += hist[b];
    part[t] = ssum;
    __syncthreads();
    if (t == 0) {
        unsigned run = 0;
        for (int i = 1023; i >= 0; i--) { suf[i] = run; run += part[i]; }
        int tc = 0;
        for (int i = 1023; i >= 0; i--) {
            if (suf[i] < KTOP && suf[i] + part[i] >= KTOP) { tc = i; break; }
        }
        unsigned c = suf[tc];
        unsigned B = tc * 64;
        for (int b = tc*64 + 63; b >= tc*64; b--) {
            c += hist[b];
            if (c >= KTOP) { B = (unsigned)b; break; }
        }
        meta[0] = B;
        meta[1] = 0;
    }
}

__global__ void collect_kernel(const float* __restrict__ hm,
                               unsigned* __restrict__ meta,
                               unsigned long long* __restrict__ cand)
{
    int i = blockIdx.x * 256 + threadIdx.x;
    if (i >= NSC) return;
    float sc = 1.f / (1.f + expf(-hm[i]));
    unsigned key = __float_as_uint(sc);
    if ((key >> 16) >= meta[0]) {
        unsigned pos = atomicAdd(&meta[1], 1u);
        if (pos < CAND_CAP)
            cand[pos] = ((unsigned long long)key << 32) | (unsigned)(0xFFFFFFFFu - (unsigned)i);
    }
}

__global__ void topk_decode_kernel(const unsigned* __restrict__ meta,
                                   const unsigned long long* __restrict__ cand,
                                   const float* __restrict__ P,
                                   float* __restrict__ dout)
{
    extern __shared__ unsigned long long s[];
    __shared__ unsigned long long red[512];
    const int t = threadIdx.x;
    unsigned n = meta[1];
    if (n > CAND_CAP) n = CAND_CAP;

    if (n <= SORT_M) {
        for (int i = t; i < SORT_M; i += 512) s[i] = (i < (int)n) ? cand[i] : 0ULL;
        __syncthreads();
        for (unsigned k = 2; k <= SORT_M; k <<= 1) {
            for (unsigned j = k >> 1; j > 0; j >>= 1) {
                for (unsigned i = t; i < SORT_M; i += 512) {
                    unsigned ixj = i ^ j;
                    if (ixj > i) {
                        unsigned long long a = s[i], b = s[ixj];
                        bool desc = ((i & k) == 0);
                        if (desc ? (a < b) : (a > b)) { s[i] = b; s[ixj] = a; }
                    }
                }
                __syncthreads();
            }
        }
    } else {
        unsigned long long last = 0xFFFFFFFFFFFFFFFFULL;
        for (int slot = 0; slot < KTOP; slot++) {
            unsigned long long best = 0;
            for (unsigned i = t; i < n; i += 512) {
                unsigned long long v = cand[i];
                if (v < last && v > best) best = v;
            }
            red[t] = best;
            __syncthreads();
            for (int off = 256; off > 0; off >>= 1) {
                if (t < off) { if (red[t+off] > red[t]) red[t] = red[t+off]; }
                __syncthreads();
            }
            if (t == 0) s[slot] = red[0];
            last = red[0];
            __syncthreads();
        }
    }
    __syncthreads();

    if (t < KTOP) {
        unsigned long long e = s[t];
        unsigned key = (unsigned)(e >> 32);
        unsigned idx = 0xFFFFFFFFu - (unsigned)(e & 0xFFFFFFFFu);
        int cls = (int)(idx / HWSZ);
        int sp  = (int)(idx % HWSZ);
        float ys = (float)(sp / WW);
        float xs = (float)(sp % WW);
        float shm = __uint_as_float(key);

        float ct0 = P[3*HWSZ + sp], ct1 = P[4*HWSZ + sp];
        float cz  = P[5*HWSZ + sp];
        float d0  = expf(P[6*HWSZ + sp]);
        float d1  = expf(P[7*HWSZ + sp]);
        float d2  = expf(P[8*HWSZ + sp]);
        float r0  = P[9*HWSZ + sp], r1 = P[10*HWSZ + sp];
        float iou = P[11*HWSZ + sp];

        float xg = (xs + ct0) * 4.0f * 0.1f + (-75.2f);
        float yg = (ys + ct1) * 4.0f * 0.1f + (-75.2f);
        float heading = atan2f(r1, r0);
        iou = (iou + 1.f) * 0.5f;
        iou = fminf(fmaxf(iou, 0.f), 1.f);
        const float RECT[3] = {0.68f, 0.71f, 0.65f};
        float r = RECT[cls];
        float score = powf(shm, 1.f - r) * powf(iou, r);
        score = (score > 0.1f) ? score : 0.f;

        dout[t*7+0] = xg;  dout[t*7+1] = yg;  dout[t*7+2] = cz;
        dout[t*7+3] = d0;  dout[t*7+4] = d1;  dout[t*7+5] = d2;
        dout[t*7+6] = heading;
        dout[3500 + t] = score;
        dout[4000 + t] = (float)cls;
    }
}

// ---------------------------------------------------------------------------
extern "C" void kernel_launch(void* const* d_in, const int* in_sizes, int n_in,
                              void* d_out, int out_size, void* d_ws, size_t ws_size,
                              hipStream_t stream)
{
    const float* x    = (const float*)d_in[0];   // [256][376][376]
    const float* W_sh = (const float*)d_in[1];   // [64][256][9]
    const float* bn_sh= (const float*)d_in[2];   // [4][64]
    const float* W1s  = (const float*)d_in[3];   // [6][64][64][9]
    const float* bn1s = (const float*)d_in[4];   // [6][4][64]
    const float* W2s  = (const float*)d_in[5];   // [6][3][64][9]
    const float* b2s  = (const float*)d_in[6];   // [6][3]
    float* dout = (float*)d_out;

    char* ws = (char*)d_ws;
    const size_t OFF_SHARED = 0;
    const size_t OFF_H1     = OFF_SHARED + (size_t)64*HWSZ*4;   // 36.19MB
    const size_t OFF_OUTS   = OFF_H1     + (size_t)64*HWSZ*4;
    const size_t OFF_HIST   = OFF_OUTS   + (size_t)12*HWSZ*4;
    const size_t OFF_META   = OFF_HIST   + (size_t)NBIN*4;
    const size_t OFF_CAND   = OFF_META   + 256;
    // reordered weights OVERLAP hist/meta/cand: rw live only during convs.
    const size_t OFF_RWSH   = OFF_HIST;                          // 196608 f
    const size_t OFF_RWBR   = OFF_RWSH + (size_t)196608*4;       // 294912 f
    const size_t OFF_RWHD   = OFF_RWBR + (size_t)294912*4;       // 10368 f

    float* f_shared = (float*)(ws + OFF_SHARED);
    float* f_h1     = (float*)(ws + OFF_H1);
    float* f_outs   = (float*)(ws + OFF_OUTS);
    unsigned* hist  = (unsigned*)(ws + OFF_HIST);
    unsigned* meta  = (unsigned*)(ws + OFF_META);
    unsigned long long* cand = (unsigned long long*)(ws + OFF_CAND);
    float* rwsh = (float*)(ws + OFF_RWSH);
    float* rwbr = (float*)(ws + OFF_RWBR);
    float* rwhd = (float*)(ws + OFF_RWHD);

    dim3 blk(256);

    // ---- weight reorders ----
    reorder_w12_kernel<<<(196608+255)/256, blk, 0, stream>>>(W_sh, rwsh, 256, 196608);
    reorder_w12_kernel<<<(294912+255)/256, blk, 0, stream>>>(W1s,  rwbr,  64, 294912);
    reorder_w_kernel<<<(10368+255)/256,  blk, 0, stream>>>(W2s, rwhd, 64, HICB, 3, 10368);

    // ---- convs ----
    dim3 gconv(6, 47);       // 64x8 tiles
    dim3 ghead(12, 6);       // 32x64 tiles
    conv64v2_kernel<256><<<gconv, blk, 0, stream>>>(x, rwsh, bn_sh, f_shared);

    const int planebase[6] = {0, 3, 5, 6, 9, 11};
    const int nch[6]       = {3, 2, 1, 3, 2, 1};
    for (int i = 0; i < 6; i++) {
        conv64v2_kernel<64><<<gconv, blk, 0, stream>>>(
            f_shared, rwbr + (size_t)i*49152, bn1s + (size_t)i*4*64, f_h1);
        head_kernel<<<ghead, blk, 0, stream>>>(
            f_h1, rwhd + (size_t)i*1728, b2s + (size_t)i*3,
            f_outs + (size_t)planebase[i]*HWSZ, nch[i]);
    }

    // ---- top-k select + decode ----
    hipMemsetAsync(hist, 0, (size_t)NBIN*4, stream);
    dim3 gscan((NSC + 255)/256);
    hist_kernel<<<gscan, blk, 0, stream>>>(f_outs, hist);
    scan_kernel<<<1, 1024, 0, stream>>>(hist, meta);
    collect_kernel<<<gscan, blk, 0, stream>>>(f_outs, meta, cand);
    topk_decode_kernel<<<1, 512, SORT_M*sizeof(unsigned long long), stream>>>(
        meta, cand, f_outs, dout);

    (void)in_sizes; (void)n_in; (void)out_size; (void)ws_size;
}

// Round 4
// 2710.090 us; speedup vs baseline: 1.6890x; 1.6890x over previous
//
#include <hip/hip_runtime.h>
#include <math.h>

#define HH 376
#define WW 376
#define HWSZ (HH*WW)          // 141376
#define NSC (3*HWSZ)          // 424128
#define KTOP 500
#define CAND_CAP 65536
#define SORT_M 4096
#define NBIN 65536

// conv64v4 tiling: 32x8 px tile, 512 threads (8 waves), wave = 8 ocs
#define ICB2 8
#define C_SINW 34
#define C_SINH 10
#define C_NLOAD (ICB2*C_SINH*C_SINW)   // 2720

// head2 tiling: 32x16 px tile, 256 threads, ICB 4
#define H2_ICB 4
#define H2_SINH 18
#define H2_SINW 34
#define H2_NLOAD (H2_ICB*H2_SINH*H2_SINW)  // 2448

// ---------------------------------------------------------------------------
// Weight reorder -> [chunk][icl][64][12] (9 real + 3 pad). Offset for
// (ic, oc) is ic*768 + oc*12 -- wave-uniform in the conv kernel.
// ---------------------------------------------------------------------------
__global__ void reorder_w12_kernel(const float* __restrict__ src, float* __restrict__ dst,
                                   int IC, int total)
{
    int i = blockIdx.x*256 + threadIdx.x;
    if (i >= total) return;
    int per = IC*64*12;
    int b  = i / per;
    int r  = i - b*per;
    int chunk = r / (ICB2*64*12);
    int r2 = r - chunk*(ICB2*64*12);
    int icl = r2 / (64*12);
    int r3  = r2 - icl*(64*12);
    int oc  = r3 / 12;
    int k   = r3 - oc*12;
    float v = 0.f;
    if (k < 9) {
        int ic = chunk*ICB2 + icl;
        v = src[(size_t)b*64*IC*9 + ((size_t)oc*IC + ic)*9 + k];
    }
    dst[i] = v;
}

// head weight reorder: [b][chunk][icl][3][9]; offset (ic*27 + o*9) uniform.
__global__ void reorder_w_kernel(const float* __restrict__ src, float* __restrict__ dst,
                                 int IC, int ICB, int OC, int total)
{
    int i = blockIdx.x*256 + threadIdx.x;
    if (i >= total) return;
    int per = OC*IC*9;
    int b = i / per;
    int j = i - b*per;
    int chunksz = ICB*OC*9;
    int chunk = j / chunksz;
    int r = j - chunk*chunksz;
    int icl = r / (OC*9);
    int rr = r - icl*(OC*9);
    int oc = rr / 9;
    int kk = rr - oc*9;
    int ic = chunk*ICB + icl;
    dst[i] = src[b*per + (oc*IC + ic)*9 + kk];
}

// ---------------------------------------------------------------------------
// conv64v4: 3x3 SAME conv, IC -> 64 oc, BN+ReLU. 512-thread block, 32x8 tile.
// Wave w handles ocs w*8..w*8+7 (wave-uniform -> weights via SCALAR loads,
// zero DS / zero VALU cost). Lane: col = tid&31, row-half rh = (tid>>5)&1
// (rows rh*4..rh*4+3). acc = 8x4 = 32 VGPRs; vin = 6x3 = 18 VGPRs.
// Per ic: 18 ds_read_b32 + 72 s_load + 288 v_fma.
// Accumulation order identical to rounds 2/3 (ic asc, w0..w8 chain).
// ---------------------------------------------------------------------------
template<int IC>
__global__ __launch_bounds__(512,4) void conv64v4_kernel(
    const float* __restrict__ in,    // [IC][H][W]
    const float* __restrict__ rw,    // [IC][64][12] reordered+padded
    const float* __restrict__ bnp,   // [4][64]
    float* __restrict__ out)         // [64][H][W]
{
    __shared__ float s_in[ICB2][C_SINH][C_SINW];

    const int tid  = threadIdx.x;
    const int x0   = blockIdx.x * 32;
    const int y0   = blockIdx.y * 8;
    const int col  = tid & 31;
    const int rh   = (tid >> 5) & 1;         // row half: rows rh*4 .. rh*4+3
    const int uslot = __builtin_amdgcn_readfirstlane((int)(threadIdx.x >> 6)); // 0..7

    float acc[8][4];
#pragma unroll
    for (int o = 0; o < 8; o++)
#pragma unroll
        for (int j = 0; j < 4; j++) acc[o][j] = 0.f;

    // ---- staging plan: C_NLOAD=2720 elements, 6 slots x 512 threads ----
    int offs[6];
    bool val[6];
#pragma unroll
    for (int k = 0; k < 6; k++) {
        int idx = tid + k*512;
        int ic  = idx / (C_SINH*C_SINW);
        int rem = idx - ic*(C_SINH*C_SINW);
        int r   = rem / C_SINW;
        int c   = rem - r*C_SINW;
        int gy  = y0 + r - 1;
        int gx  = x0 + c - 1;
        val[k]  = (idx < C_NLOAD) && (gy >= 0) && (gy < HH) && (gx >= 0) && (gx < WW);
        offs[k] = ic*HWSZ + gy*WW + gx;
    }
    float pf[6];
    int icadv = 0;
    auto do_prefetch = [&]() {
#pragma unroll
        for (int k = 0; k < 6; k++)
            pf[k] = val[k] ? in[offs[k] + icadv] : 0.f;
    };
    do_prefetch();

    float* flat = &s_in[0][0][0];

    for (int ic0 = 0; ic0 < IC; ic0 += ICB2) {
        __syncthreads();                       // previous compute done
#pragma unroll
        for (int k = 0; k < 5; k++) flat[tid + k*512] = pf[k];
        if (tid < C_NLOAD - 5*512) flat[tid + 5*512] = pf[5];
        __syncthreads();
        if (ic0 + ICB2 < IC) { icadv += ICB2*HWSZ; do_prefetch(); }

#pragma unroll 1
        for (int ic = 0; ic < ICB2; ic++) {
            float vin[6][3];
#pragma unroll
            for (int r = 0; r < 6; r++) {
                vin[r][0] = s_in[ic][rh*4 + r][col];
                vin[r][1] = s_in[ic][rh*4 + r][col+1];
                vin[r][2] = s_in[ic][rh*4 + r][col+2];
            }
            // wave-uniform weight base for this ic
            const float* wic = rw + (ic0 + ic)*768 + uslot*96;  // 8 ocs * 12
#pragma unroll
            for (int o = 0; o < 8; o++) {
                const float* wp = wic + o*12;
                float w0=wp[0],w1=wp[1],w2=wp[2],w3=wp[3],w4=wp[4],
                      w5=wp[5],w6=wp[6],w7=wp[7],w8=wp[8];
#pragma unroll
                for (int j = 0; j < 4; j++) {
                    float s = acc[o][j];
                    s = fmaf(w0, vin[j  ][0], s);
                    s = fmaf(w1, vin[j  ][1], s);
                    s = fmaf(w2, vin[j  ][2], s);
                    s = fmaf(w3, vin[j+1][0], s);
                    s = fmaf(w4, vin[j+1][1], s);
                    s = fmaf(w5, vin[j+1][2], s);
                    s = fmaf(w6, vin[j+2][0], s);
                    s = fmaf(w7, vin[j+2][1], s);
                    s = fmaf(w8, vin[j+2][2], s);
                    acc[o][j] = s;
                }
            }
        }
    }

    // ---- epilogue: BN + ReLU ----
    const int gx = x0 + col;
    if (gx < WW) {
#pragma unroll
        for (int o = 0; o < 8; o++) {
            int oc = uslot*8 + o;
            float g = bnp[oc], b = bnp[64+oc], m = bnp[128+oc], v = bnp[192+oc];
            float sc = g * rsqrtf(v + 1e-5f);
            float sh = b - m * sc;
#pragma unroll
            for (int j = 0; j < 4; j++) {
                int gy = y0 + rh*4 + j;       // always < 376 (47*8 = 376)
                float valo = fmaxf(fmaf(acc[o][j], sc, sh), 0.f);
                out[(size_t)oc*HWSZ + (size_t)gy*WW + gx] = valo;
            }
        }
    }
}

// ---------------------------------------------------------------------------
// head2: 3x3 conv 64 -> nch (<=3) + bias. 256 threads, 32x16 tile, ICB=4.
// Weight offsets are THREAD-INVARIANT -> scalar loads. Thread = 1 col x
// 2 rows x 3 ocs. 288-block grid (vs 72 before).
// ---------------------------------------------------------------------------
__global__ __launch_bounds__(256,4) void head2_kernel(
    const float* __restrict__ in,    // [64][H][W]
    const float* __restrict__ rwh,   // [16][4][3][9] reordered
    const float* __restrict__ bias,  // [3]
    float* __restrict__ out,         // [nch][H][W]
    int nch)
{
    __shared__ float s_in[H2_ICB][H2_SINH][H2_SINW];

    const int tid = threadIdx.x;
    const int x0  = blockIdx.x * 32;
    const int y0  = blockIdx.y * 16;
    const int col = tid & 31;
    const int rs  = tid >> 5;            // rows 2rs, 2rs+1

    float acc[3][2];
#pragma unroll
    for (int o = 0; o < 3; o++) { acc[o][0] = 0.f; acc[o][1] = 0.f; }

    int offs[10];
    bool val[10];
#pragma unroll
    for (int k = 0; k < 10; k++) {
        int idx = tid + k*256;
        int ic  = idx / (H2_SINH*H2_SINW);
        int rem = idx - ic*(H2_SINH*H2_SINW);
        int r   = rem / H2_SINW;
        int c   = rem - r*H2_SINW;
        int gy  = y0 + r - 1;
        int gx  = x0 + c - 1;
        val[k]  = (idx < H2_NLOAD) && (gy >= 0) && (gy < HH) && (gx >= 0) && (gx < WW);
        offs[k] = ic*HWSZ + gy*WW + gx;
    }
    float pf[10];
    int icadv = 0;
    auto do_prefetch = [&]() {
#pragma unroll
        for (int k = 0; k < 10; k++)
            pf[k] = val[k] ? in[offs[k] + icadv] : 0.f;
    };
    do_prefetch();

    float* flat = &s_in[0][0][0];

    for (int ic0 = 0; ic0 < 64; ic0 += H2_ICB) {
        __syncthreads();
#pragma unroll
        for (int k = 0; k < 9; k++) flat[tid + k*256] = pf[k];
        if (tid < H2_NLOAD - 9*256) flat[tid + 9*256] = pf[9];
        __syncthreads();
        if (ic0 + H2_ICB < 64) { icadv += H2_ICB*HWSZ; do_prefetch(); }

#pragma unroll 1
        for (int ic = 0; ic < H2_ICB; ic++) {
            float vin[4][3];
#pragma unroll
            for (int r = 0; r < 4; r++) {
                vin[r][0] = s_in[ic][2*rs + r][col];
                vin[r][1] = s_in[ic][2*rs + r][col+1];
                vin[r][2] = s_in[ic][2*rs + r][col+2];
            }
            const float* wic = rwh + (ic0 + ic)*27;   // thread-invariant
#pragma unroll
            for (int o = 0; o < 3; o++) {
                const float* wp = wic + o*9;
                float w0=wp[0],w1=wp[1],w2=wp[2],w3=wp[3],w4=wp[4],
                      w5=wp[5],w6=wp[6],w7=wp[7],w8=wp[8];
#pragma unroll
                for (int j = 0; j < 2; j++) {
                    float s = acc[o][j];
                    s = fmaf(w0, vin[j  ][0], s);
                    s = fmaf(w1, vin[j  ][1], s);
                    s = fmaf(w2, vin[j  ][2], s);
                    s = fmaf(w3, vin[j+1][0], s);
                    s = fmaf(w4, vin[j+1][1], s);
                    s = fmaf(w5, vin[j+1][2], s);
                    s = fmaf(w6, vin[j+2][0], s);
                    s = fmaf(w7, vin[j+2][1], s);
                    s = fmaf(w8, vin[j+2][2], s);
                    acc[o][j] = s;
                }
            }
        }
    }

    const int gx = x0 + col;
    if (gx < WW) {
#pragma unroll
        for (int o = 0; o < 3; o++) {
            if (o < nch) {
                float bo = bias[o];
#pragma unroll
                for (int j = 0; j < 2; j++) {
                    int gy = y0 + 2*rs + j;
                    if (gy < HH)
                        out[(size_t)o*HWSZ + (size_t)gy*WW + gx] = acc[o][j] + bo;
                }
            }
        }
    }
}

// ---------------------------------------------------------------------------
// Top-K machinery (verified correct, unchanged).
// ---------------------------------------------------------------------------
__global__ void hist_kernel(const float* __restrict__ hm, unsigned* __restrict__ hist)
{
    int i = blockIdx.x * 256 + threadIdx.x;
    if (i < NSC) {
        float sc = 1.f / (1.f + expf(-hm[i]));
        unsigned key = __float_as_uint(sc);
        atomicAdd(&hist[key >> 16], 1u);
    }
}

__global__ void scan_kernel(const unsigned* __restrict__ hist, unsigned* __restrict__ meta)
{
    __shared__ unsigned part[1024];
    __shared__ unsigned suf[1024];
    const int t = threadIdx.x;
    unsigned ssum = 0;
    for (int b = t*64; b < t*64 + 64; b++) ssum += hist[b];
    part[t] = ssum;
    __syncthreads();
    if (t == 0) {
        unsigned run = 0;
        for (int i = 1023; i >= 0; i--) { suf[i] = run; run += part[i]; }
        int tc = 0;
        for (int i = 1023; i >= 0; i--) {
            if (suf[i] < KTOP && suf[i] + part[i] >= KTOP) { tc = i; break; }
        }
        unsigned c = suf[tc];
        unsigned B = tc * 64;
        for (int b = tc*64 + 63; b >= tc*64; b--) {
            c += hist[b];
            if (c >= KTOP) { B = (unsigned)b; break; }
        }
        meta[0] = B;
        meta[1] = 0;
    }
}

__global__ void collect_kernel(const float* __restrict__ hm,
                               unsigned* __restrict__ meta,
                               unsigned long long* __restrict__ cand)
{
    int i = blockIdx.x * 256 + threadIdx.x;
    if (i >= NSC) return;
    float sc = 1.f / (1.f + expf(-hm[i]));
    unsigned key = __float_as_uint(sc);
    if ((key >> 16) >= meta[0]) {
        unsigned pos = atomicAdd(&meta[1], 1u);
        if (pos < CAND_CAP)
            cand[pos] = ((unsigned long long)key << 32) | (unsigned)(0xFFFFFFFFu - (unsigned)i);
    }
}

__global__ void topk_decode_kernel(const unsigned* __restrict__ meta,
                                   const unsigned long long* __restrict__ cand,
                                   const float* __restrict__ P,
                                   float* __restrict__ dout)
{
    extern __shared__ unsigned long long s[];
    __shared__ unsigned long long red[512];
    const int t = threadIdx.x;
    unsigned n = meta[1];
    if (n > CAND_CAP) n = CAND_CAP;

    if (n <= SORT_M) {
        for (int i = t; i < SORT_M; i += 512) s[i] = (i < (int)n) ? cand[i] : 0ULL;
        __syncthreads();
        for (unsigned k = 2; k <= SORT_M; k <<= 1) {
            for (unsigned j = k >> 1; j > 0; j >>= 1) {
                for (unsigned i = t; i < SORT_M; i += 512) {
                    unsigned ixj = i ^ j;
                    if (ixj > i) {
                        unsigned long long a = s[i], b = s[ixj];
                        bool desc = ((i & k) == 0);
                        if (desc ? (a < b) : (a > b)) { s[i] = b; s[ixj] = a; }
                    }
                }
                __syncthreads();
            }
        }
    } else {
        unsigned long long last = 0xFFFFFFFFFFFFFFFFULL;
        for (int slot = 0; slot < KTOP; slot++) {
            unsigned long long best = 0;
            for (unsigned i = t; i < n; i += 512) {
                unsigned long long v = cand[i];
                if (v < last && v > best) best = v;
            }
            red[t] = best;
            __syncthreads();
            for (int off = 256; off > 0; off >>= 1) {
                if (t < off) { if (red[t+off] > red[t]) red[t] = red[t+off]; }
                __syncthreads();
            }
            if (t == 0) s[slot] = red[0];
            last = red[0];
            __syncthreads();
        }
    }
    __syncthreads();

    if (t < KTOP) {
        unsigned long long e = s[t];
        unsigned key = (unsigned)(e >> 32);
        unsigned idx = 0xFFFFFFFFu - (unsigned)(e & 0xFFFFFFFFu);
        int cls = (int)(idx / HWSZ);
        int sp  = (int)(idx % HWSZ);
        float ys = (float)(sp / WW);
        float xs = (float)(sp % WW);
        float shm = __uint_as_float(key);

        float ct0 = P[3*HWSZ + sp], ct1 = P[4*HWSZ + sp];
        float cz  = P[5*HWSZ + sp];
        float d0  = expf(P[6*HWSZ + sp]);
        float d1  = expf(P[7*HWSZ + sp]);
        float d2  = expf(P[8*HWSZ + sp]);
        float r0  = P[9*HWSZ + sp], r1 = P[10*HWSZ + sp];
        float iou = P[11*HWSZ + sp];

        float xg = (xs + ct0) * 4.0f * 0.1f + (-75.2f);
        float yg = (ys + ct1) * 4.0f * 0.1f + (-75.2f);
        float heading = atan2f(r1, r0);
        iou = (iou + 1.f) * 0.5f;
        iou = fminf(fmaxf(iou, 0.f), 1.f);
        const float RECT[3] = {0.68f, 0.71f, 0.65f};
        float r = RECT[cls];
        float score = powf(shm, 1.f - r) * powf(iou, r);
        score = (score > 0.1f) ? score : 0.f;

        dout[t*7+0] = xg;  dout[t*7+1] = yg;  dout[t*7+2] = cz;
        dout[t*7+3] = d0;  dout[t*7+4] = d1;  dout[t*7+5] = d2;
        dout[t*7+6] = heading;
        dout[3500 + t] = score;
        dout[4000 + t] = (float)cls;
    }
}

// ---------------------------------------------------------------------------
extern "C" void kernel_launch(void* const* d_in, const int* in_sizes, int n_in,
                              void* d_out, int out_size, void* d_ws, size_t ws_size,
                              hipStream_t stream)
{
    const float* x    = (const float*)d_in[0];   // [256][376][376]
    const float* W_sh = (const float*)d_in[1];   // [64][256][9]
    const float* bn_sh= (const float*)d_in[2];   // [4][64]
    const float* W1s  = (const float*)d_in[3];   // [6][64][64][9]
    const float* bn1s = (const float*)d_in[4];   // [6][4][64]
    const float* W2s  = (const float*)d_in[5];   // [6][3][64][9]
    const float* b2s  = (const float*)d_in[6];   // [6][3]
    float* dout = (float*)d_out;

    char* ws = (char*)d_ws;
    const size_t OFF_SHARED = 0;
    const size_t OFF_H1     = OFF_SHARED + (size_t)64*HWSZ*4;
    const size_t OFF_OUTS   = OFF_H1     + (size_t)64*HWSZ*4;
    const size_t OFF_HIST   = OFF_OUTS   + (size_t)12*HWSZ*4;
    const size_t OFF_META   = OFF_HIST   + (size_t)NBIN*4;
    const size_t OFF_CAND   = OFF_META   + 256;
    // reordered weights OVERLAP hist/meta/cand: rw live only during convs.
    const size_t OFF_RWSH   = OFF_HIST;                          // 196608 f
    const size_t OFF_RWBR   = OFF_RWSH + (size_t)196608*4;       // 294912 f
    const size_t OFF_RWHD   = OFF_RWBR + (size_t)294912*4;       // 10368 f

    float* f_shared = (float*)(ws + OFF_SHARED);
    float* f_h1     = (float*)(ws + OFF_H1);
    float* f_outs   = (float*)(ws + OFF_OUTS);
    unsigned* hist  = (unsigned*)(ws + OFF_HIST);
    unsigned* meta  = (unsigned*)(ws + OFF_META);
    unsigned long long* cand = (unsigned long long*)(ws + OFF_CAND);
    float* rwsh = (float*)(ws + OFF_RWSH);
    float* rwbr = (float*)(ws + OFF_RWBR);
    float* rwhd = (float*)(ws + OFF_RWHD);

    dim3 blk(256);

    // ---- weight reorders ----
    reorder_w12_kernel<<<(196608+255)/256, blk, 0, stream>>>(W_sh, rwsh, 256, 196608);
    reorder_w12_kernel<<<(294912+255)/256, blk, 0, stream>>>(W1s,  rwbr,  64, 294912);
    reorder_w_kernel<<<(10368+255)/256,  blk, 0, stream>>>(W2s, rwhd, 64, H2_ICB, 3, 10368);

    // ---- convs ----
    dim3 gconv(12, 47);      // 32x8 tiles
    dim3 ghead(12, 24);      // 32x16 tiles
    conv64v4_kernel<256><<<gconv, dim3(512), 0, stream>>>(x, rwsh, bn_sh, f_shared);

    const int planebase[6] = {0, 3, 5, 6, 9, 11};
    const int nch[6]       = {3, 2, 1, 3, 2, 1};
    for (int i = 0; i < 6; i++) {
        conv64v4_kernel<64><<<gconv, dim3(512), 0, stream>>>(
            f_shared, rwbr + (size_t)i*49152, bn1s + (size_t)i*4*64, f_h1);
        head2_kernel<<<ghead, blk, 0, stream>>>(
            f_h1, rwhd + (size_t)i*1728, b2s + (size_t)i*3,
            f_outs + (size_t)planebase[i]*HWSZ, nch[i]);
    }

    // ---- top-k select + decode ----
    hipMemsetAsync(hist, 0, (size_t)NBIN*4, stream);
    dim3 gscan((NSC + 255)/256);
    hist_kernel<<<gscan, blk, 0, stream>>>(f_outs, hist);
    scan_kernel<<<1, 1024, 0, stream>>>(hist, meta);
    collect_kernel<<<gscan, blk, 0, stream>>>(f_outs, meta, cand);
    topk_decode_kernel<<<1, 512, SORT_M*sizeof(unsigned long long), stream>>>(
        meta, cand, f_outs, dout);

    (void)in_sizes; (void)n_in; (void)out_size; (void)ws_size;
}

// Round 5
// 1897.036 us; speedup vs baseline: 2.4128x; 1.4286x over previous
//
#include <hip/hip_runtime.h>
#include <math.h>

#define HH 376
#define WW 376
#define HWSZ (HH*WW)          // 141376
#define NSC (3*HWSZ)          // 424128
#define KTOP 500
#define CAND_CAP 65536
#define SORT_M 4096
#define NBIN 65536

// convb tiling: 32x8 px tile, 256 threads (4 waves), wave = 8 ocs,
// block handles 32 ocs (blockIdx.z parity selects which half).
#define CICB 4
#define CSINW 34
#define CSINH 10
#define CNLOAD (CICB*CSINH*CSINW)   // 1360

// head tiling: 32x16 px tile, 256 threads, ICB 4
#define H2_ICB 4
#define H2_SINH 18
#define H2_SINW 34
#define H2_NLOAD (H2_ICB*H2_SINH*H2_SINW)  // 2448

__device__ __constant__ int d_pb[6] = {0, 3, 5, 6, 9, 11};
__device__ __constant__ int d_nc[6] = {3, 2, 1, 3, 2, 1};

// ---------------------------------------------------------------------------
// Weight reorder -> ic-major [b][IC][64][12] (9 real + 3 pad); offset for
// (ic,oc) = ic*768 + oc*12, wave-uniform in the conv kernel (scalar loads).
// ---------------------------------------------------------------------------
__global__ void reorder_w12_kernel(const float* __restrict__ src, float* __restrict__ dst,
                                   int IC, int total)
{
    int i = blockIdx.x*256 + threadIdx.x;
    if (i >= total) return;
    int per = IC*64*12;
    int b  = i / per;
    int r  = i - b*per;
    int ic = r / 768;
    int r3 = r - ic*768;
    int oc = r3 / 12;
    int k  = r3 - oc*12;
    float v = 0.f;
    if (k < 9)
        v = src[(size_t)b*64*IC*9 + ((size_t)oc*IC + ic)*9 + k];
    dst[i] = v;
}

// head weight reorder: ic-major [b][64][3][9]; offset ic*27 + o*9 uniform.
__global__ void reorder_wh_kernel(const float* __restrict__ src, float* __restrict__ dst,
                                  int total)
{
    int i = blockIdx.x*256 + threadIdx.x;
    if (i >= total) return;
    int per = 3*64*9;
    int b = i / per;
    int j = i - b*per;
    int ic = j / 27;
    int rr = j - ic*27;
    int oc = rr / 9;
    int kk = rr - oc*9;
    dst[i] = src[b*per + (oc*64 + ic)*9 + kk];
}

// ---------------------------------------------------------------------------
// convb: 3x3 SAME conv, IC -> 64 oc (32 per block), BN+ReLU. 256-thread
// block, 32x8 tile. blockIdx.z = br*2 + half. Wave w -> ocs half*32+w*8..+7
// (wave-uniform -> weights via SCALAR loads). Lane: col=tid&31,
// rh=(tid>>5)&1 (rows rh*4..rh*4+3). acc=32, vin=18 VGPRs.
// Accumulation order identical to rounds 2-4 (ic asc, w0..w8 chain) --
// required for bit-stable top-k ordering.
// ---------------------------------------------------------------------------
template<int IC>
__global__ __launch_bounds__(256) void convb_kernel(
    const float* __restrict__ in,    // [IC][H][W]
    const float* __restrict__ rw,    // [br][IC][64][12]
    const float* __restrict__ bn,    // [br][4][64]
    float* __restrict__ out)         // [br][64][H][W]
{
    __shared__ float s_in[CICB][CSINH][CSINW];

    const int tid  = threadIdx.x;
    const int x0   = blockIdx.x * 32;
    const int y0   = blockIdx.y * 8;
    const int br   = blockIdx.z >> 1;
    const int half = blockIdx.z & 1;
    const int col  = tid & 31;
    const int rh   = (tid >> 5) & 1;
    const int uslot = __builtin_amdgcn_readfirstlane(tid >> 6);  // 0..3

    const float* rwb = rw + (size_t)br * IC * 768;
    const float* bnb = bn + br * 256;
    float* outb = out + (size_t)br * 64 * HWSZ;

    float acc[8][4];
#pragma unroll
    for (int o = 0; o < 8; o++)
#pragma unroll
        for (int j = 0; j < 4; j++) acc[o][j] = 0.f;

    float pf[6];
    int icbase = 0;
    auto do_prefetch = [&]() {
#pragma unroll
        for (int k = 0; k < 6; k++) {
            int idx = tid + k*256;
            int ic  = idx / 340;
            int rem = idx - ic*340;
            int r   = rem / 34;
            int c   = rem - r*34;
            int gy  = y0 + r - 1;
            int gx  = x0 + c - 1;
            bool v  = (idx < CNLOAD) && (gy >= 0) && (gy < HH) && (gx >= 0) && (gx < WW);
            pf[k] = v ? in[(size_t)(icbase+ic)*HWSZ + gy*WW + gx] : 0.f;
        }
    };
    do_prefetch();

    float* flat = &s_in[0][0][0];

    for (int ic0 = 0; ic0 < IC; ic0 += CICB) {
        __syncthreads();                       // previous compute done
#pragma unroll
        for (int k = 0; k < 5; k++) flat[tid + k*256] = pf[k];
        if (tid < CNLOAD - 5*256) flat[tid + 5*256] = pf[5];
        __syncthreads();
        if (ic0 + CICB < IC) { icbase = ic0 + CICB; do_prefetch(); }

#pragma unroll 1
        for (int ic = 0; ic < CICB; ic++) {
            float vin[6][3];
#pragma unroll
            for (int r = 0; r < 6; r++) {
                vin[r][0] = s_in[ic][rh*4 + r][col];
                vin[r][1] = s_in[ic][rh*4 + r][col+1];
                vin[r][2] = s_in[ic][rh*4 + r][col+2];
            }
            // wave-uniform weight base: 8 ocs x 12 floats
            const float* wic = rwb + (size_t)(ic0 + ic)*768 + half*384 + uslot*96;
#pragma unroll
            for (int o = 0; o < 8; o++) {
                const float* wp = wic + o*12;
                float w0=wp[0],w1=wp[1],w2=wp[2],w3=wp[3],w4=wp[4],
                      w5=wp[5],w6=wp[6],w7=wp[7],w8=wp[8];
#pragma unroll
                for (int j = 0; j < 4; j++) {
                    float s = acc[o][j];
                    s = fmaf(w0, vin[j  ][0], s);
                    s = fmaf(w1, vin[j  ][1], s);
                    s = fmaf(w2, vin[j  ][2], s);
                    s = fmaf(w3, vin[j+1][0], s);
                    s = fmaf(w4, vin[j+1][1], s);
                    s = fmaf(w5, vin[j+1][2], s);
                    s = fmaf(w6, vin[j+2][0], s);
                    s = fmaf(w7, vin[j+2][1], s);
                    s = fmaf(w8, vin[j+2][2], s);
                    acc[o][j] = s;
                }
            }
        }
    }

    // ---- epilogue: BN + ReLU ----
    const int gx = x0 + col;
    if (gx < WW) {
#pragma unroll
        for (int o = 0; o < 8; o++) {
            int oc = half*32 + uslot*8 + o;
            float g = bnb[oc], b = bnb[64+oc], m = bnb[128+oc], v = bnb[192+oc];
            float sc = g * rsqrtf(v + 1e-5f);
            float sh = b - m * sc;
#pragma unroll
            for (int j = 0; j < 4; j++) {
                int gy = y0 + rh*4 + j;       // 47*8 = 376 exact, no guard
                float valo = fmaxf(fmaf(acc[o][j], sc, sh), 0.f);
                outb[(size_t)oc*HWSZ + (size_t)gy*WW + gx] = valo;
            }
        }
    }
}

// ---------------------------------------------------------------------------
// head3: 3x3 conv 64 -> nch (<=3) + bias. 256 threads, 32x16 tile, ICB=4.
// Branch = br_base + blockIdx.z; weights thread-invariant -> scalar loads.
// The hm branch (br==0) also histograms its sigmoid scores (hist zeroed at
// launch start).
// ---------------------------------------------------------------------------
__global__ __launch_bounds__(256) void head3_kernel(
    const float* __restrict__ in_base,
    size_t in_br_stride,                 // elements; 64*HWSZ fused, 0 fallback
    int br_base,
    const float* __restrict__ rwh_all,   // [6][64][3][9]
    const float* __restrict__ bias_all,  // [6][3]
    float* __restrict__ outs,            // 12 planes
    unsigned* __restrict__ hist)
{
    __shared__ float s_in[H2_ICB][H2_SINH][H2_SINW];

    const int br  = br_base + blockIdx.z;
    const float* in = in_base + (size_t)blockIdx.z * in_br_stride;
    const float* rwh = rwh_all + (size_t)br * 1728;
    const float* bias = bias_all + br * 3;
    float* out = outs + (size_t)d_pb[br] * HWSZ;
    const int nch = d_nc[br];

    const int tid = threadIdx.x;
    const int x0  = blockIdx.x * 32;
    const int y0  = blockIdx.y * 16;
    const int col = tid & 31;
    const int rs  = tid >> 5;            // rows 2rs, 2rs+1

    float acc[3][2];
#pragma unroll
    for (int o = 0; o < 3; o++) { acc[o][0] = 0.f; acc[o][1] = 0.f; }

    int offs[10];
    bool val[10];
#pragma unroll
    for (int k = 0; k < 10; k++) {
        int idx = tid + k*256;
        int ic  = idx / (H2_SINH*H2_SINW);
        int rem = idx - ic*(H2_SINH*H2_SINW);
        int r   = rem / H2_SINW;
        int c   = rem - r*H2_SINW;
        int gy  = y0 + r - 1;
        int gx  = x0 + c - 1;
        val[k]  = (idx < H2_NLOAD) && (gy >= 0) && (gy < HH) && (gx >= 0) && (gx < WW);
        offs[k] = ic*HWSZ + gy*WW + gx;
    }
    float pf[10];
    int icadv = 0;
    auto do_prefetch = [&]() {
#pragma unroll
        for (int k = 0; k < 10; k++)
            pf[k] = val[k] ? in[offs[k] + icadv] : 0.f;
    };
    do_prefetch();

    float* flat = &s_in[0][0][0];

    for (int ic0 = 0; ic0 < 64; ic0 += H2_ICB) {
        __syncthreads();
#pragma unroll
        for (int k = 0; k < 9; k++) flat[tid + k*256] = pf[k];
        if (tid < H2_NLOAD - 9*256) flat[tid + 9*256] = pf[9];
        __syncthreads();
        if (ic0 + H2_ICB < 64) { icadv += H2_ICB*HWSZ; do_prefetch(); }

#pragma unroll 1
        for (int ic = 0; ic < H2_ICB; ic++) {
            float vin[4][3];
#pragma unroll
            for (int r = 0; r < 4; r++) {
                vin[r][0] = s_in[ic][2*rs + r][col];
                vin[r][1] = s_in[ic][2*rs + r][col+1];
                vin[r][2] = s_in[ic][2*rs + r][col+2];
            }
            const float* wic = rwh + (ic0 + ic)*27;   // thread-invariant
#pragma unroll
            for (int o = 0; o < 3; o++) {
                const float* wp = wic + o*9;
                float w0=wp[0],w1=wp[1],w2=wp[2],w3=wp[3],w4=wp[4],
                      w5=wp[5],w6=wp[6],w7=wp[7],w8=wp[8];
#pragma unroll
                for (int j = 0; j < 2; j++) {
                    float s = acc[o][j];
                    s = fmaf(w0, vin[j  ][0], s);
                    s = fmaf(w1, vin[j  ][1], s);
                    s = fmaf(w2, vin[j  ][2], s);
                    s = fmaf(w3, vin[j+1][0], s);
                    s = fmaf(w4, vin[j+1][1], s);
                    s = fmaf(w5, vin[j+1][2], s);
                    s = fmaf(w6, vin[j+2][0], s);
                    s = fmaf(w7, vin[j+2][1], s);
                    s = fmaf(w8, vin[j+2][2], s);
                    acc[o][j] = s;
                }
            }
        }
    }

    const int gx = x0 + col;
    if (gx < WW) {
#pragma unroll
        for (int o = 0; o < 3; o++) {
            if (o < nch) {
                float bo = bias[o];
#pragma unroll
                for (int j = 0; j < 2; j++) {
                    int gy = y0 + 2*rs + j;
                    if (gy < HH) {
                        float v = acc[o][j] + bo;
                        out[(size_t)o*HWSZ + (size_t)gy*WW + gx] = v;
                        if (br == 0) {   // hm branch: histogram sigmoid bits
                            float sc = 1.f / (1.f + expf(-v));
                            atomicAdd(&hist[__float_as_uint(sc) >> 16], 1u);
                        }
                    }
                }
            }
        }
    }
}

// ---------------------------------------------------------------------------
// Top-K: histogram (in head3) -> threshold-bucket scan -> collect -> sort.
// Keys: sigmoid scores are positive floats, bit pattern order-isomorphic.
// 64-bit key (score_bits<<32)|(~idx) sorted desc == jax.lax.top_k order.
// ---------------------------------------------------------------------------
__global__ void scan_kernel(const unsigned* __restrict__ hist, unsigned* __restrict__ meta)
{
    __shared__ unsigned part[1024];
    __shared__ unsigned scn[1024];
    __shared__ int tcs;
    const int t = threadIdx.x;
    unsigned ssum = 0;
    for (int b = t*64; b < t*64 + 64; b++) ssum += hist[b];
    part[t] = ssum;
    scn[t] = ssum;
    __syncthreads();
    // Hillis-Steele inclusive SUFFIX sum over the 1024 group sums
    for (int off = 1; off < 1024; off <<= 1) {
        unsigned v = (t + off < 1024) ? scn[t + off] : 0u;
        __syncthreads();
        scn[t] += v;
        __syncthreads();
    }
    unsigned sufEx = scn[t] - part[t];
    if (sufEx < KTOP && scn[t] >= KTOP) tcs = t;   // unique crossing group
    __syncthreads();
    if (t == 0) {
        int tc = tcs;
        unsigned c = scn[tc] - part[tc];
        unsigned B = tc * 64;
        for (int b = tc*64 + 63; b >= tc*64; b--) {
            c += hist[b];
            if (c >= KTOP) { B = (unsigned)b; break; }
        }
        meta[0] = B;   // threshold bucket
        meta[1] = 0;   // candidate counter
    }
}

__global__ void collect_kernel(const float* __restrict__ hm,
                               unsigned* __restrict__ meta,
                               unsigned long long* __restrict__ cand)
{
    int i = blockIdx.x * 256 + threadIdx.x;
    if (i >= NSC) return;
    float sc = 1.f / (1.f + expf(-hm[i]));
    unsigned key = __float_as_uint(sc);
    if ((key >> 16) >= meta[0]) {
        unsigned pos = atomicAdd(&meta[1], 1u);
        if (pos < CAND_CAP)
            cand[pos] = ((unsigned long long)key << 32) | (unsigned)(0xFFFFFFFFu - (unsigned)i);
    }
}

__global__ void topk_decode_kernel(const unsigned* __restrict__ meta,
                                   const unsigned long long* __restrict__ cand,
                                   const float* __restrict__ P,
                                   float* __restrict__ dout)
{
    extern __shared__ unsigned long long s[];
    __shared__ unsigned long long red[512];
    const int t = threadIdx.x;
    unsigned n = meta[1];
    if (n > CAND_CAP) n = CAND_CAP;

    if (n <= SORT_M) {
        unsigned m = 1024;                    // n >= KTOP=500 always
        while (m < n) m <<= 1;
        for (unsigned i = t; i < m; i += 512) s[i] = (i < n) ? cand[i] : 0ULL;
        __syncthreads();
        for (unsigned k = 2; k <= m; k <<= 1) {
            for (unsigned j = k >> 1; j > 0; j >>= 1) {
                for (unsigned i = t; i < m; i += 512) {
                    unsigned ixj = i ^ j;
                    if (ixj > i) {
                        unsigned long long a = s[i], b = s[ixj];
                        bool desc = ((i & k) == 0);
                        if (desc ? (a < b) : (a > b)) { s[i] = b; s[ixj] = a; }
                    }
                }
                __syncthreads();
            }
        }
    } else {
        // fallback (never expected): O(K*n) selection
        unsigned long long last = 0xFFFFFFFFFFFFFFFFULL;
        for (int slot = 0; slot < KTOP; slot++) {
            unsigned long long best = 0;
            for (unsigned i = t; i < n; i += 512) {
                unsigned long long v = cand[i];
                if (v < last && v > best) best = v;
            }
            red[t] = best;
            __syncthreads();
            for (int off = 256; off > 0; off >>= 1) {
                if (t < off) { if (red[t+off] > red[t]) red[t] = red[t+off]; }
                __syncthreads();
            }
            if (t == 0) s[slot] = red[0];
            last = red[0];
            __syncthreads();
        }
    }
    __syncthreads();

    if (t < KTOP) {
        unsigned long long e = s[t];
        unsigned key = (unsigned)(e >> 32);
        unsigned idx = 0xFFFFFFFFu - (unsigned)(e & 0xFFFFFFFFu);
        int cls = (int)(idx / HWSZ);
        int sp  = (int)(idx % HWSZ);
        float ys = (float)(sp / WW);
        float xs = (float)(sp % WW);
        float shm = __uint_as_float(key);

        float ct0 = P[3*HWSZ + sp], ct1 = P[4*HWSZ + sp];
        float cz  = P[5*HWSZ + sp];
        float d0  = expf(P[6*HWSZ + sp]);
        float d1  = expf(P[7*HWSZ + sp]);
        float d2  = expf(P[8*HWSZ + sp]);
        float r0  = P[9*HWSZ + sp], r1 = P[10*HWSZ + sp];
        float iou = P[11*HWSZ + sp];

        float xg = (xs + ct0) * 4.0f * 0.1f + (-75.2f);
        float yg = (ys + ct1) * 4.0f * 0.1f + (-75.2f);
        float heading = atan2f(r1, r0);
        iou = (iou + 1.f) * 0.5f;
        iou = fminf(fmaxf(iou, 0.f), 1.f);
        const float RECT[3] = {0.68f, 0.71f, 0.65f};
        float r = RECT[cls];
        float score = powf(shm, 1.f - r) * powf(iou, r);
        score = (score > 0.1f) ? score : 0.f;

        dout[t*7+0] = xg;  dout[t*7+1] = yg;  dout[t*7+2] = cz;
        dout[t*7+3] = d0;  dout[t*7+4] = d1;  dout[t*7+5] = d2;
        dout[t*7+6] = heading;
        dout[3500 + t] = score;
        dout[4000 + t] = (float)cls;
    }
}

// ---------------------------------------------------------------------------
extern "C" void kernel_launch(void* const* d_in, const int* in_sizes, int n_in,
                              void* d_out, int out_size, void* d_ws, size_t ws_size,
                              hipStream_t stream)
{
    const float* x    = (const float*)d_in[0];   // [256][376][376]
    const float* W_sh = (const float*)d_in[1];   // [64][256][9]
    const float* bn_sh= (const float*)d_in[2];   // [4][64]
    const float* W1s  = (const float*)d_in[3];   // [6][64][64][9]
    const float* bn1s = (const float*)d_in[4];   // [6][4][64]
    const float* W2s  = (const float*)d_in[5];   // [6][3][64][9]
    const float* b2s  = (const float*)d_in[6];   // [6][3]
    float* dout = (float*)d_out;

    char* ws = (char*)d_ws;
    const size_t SHARED_B = (size_t)64*HWSZ*4;            // 36,192,256
    const size_t OFF_SHARED = 0;
    const size_t OFF_OUTS   = OFF_SHARED + SHARED_B;
    const size_t OFF_HIST   = OFF_OUTS   + (size_t)12*HWSZ*4;
    const size_t OFF_META   = OFF_HIST   + (size_t)NBIN*4;
    const size_t OFF_CAND   = OFF_META   + 256;
    const size_t OFF_RWSH   = OFF_CAND   + (size_t)CAND_CAP*8;
    const size_t OFF_RWBR   = OFF_RWSH   + (size_t)196608*4;
    const size_t OFF_RWHD   = OFF_RWBR   + (size_t)294912*4;
    const size_t OFF_H1     = OFF_RWHD   + (size_t)10368*4;
    const size_t NEED_FUSED = OFF_H1 + 6*SHARED_B;        // ~263 MB
    const bool fused = (ws_size >= NEED_FUSED);

    float* f_shared = (float*)(ws + OFF_SHARED);
    float* f_outs   = (float*)(ws + OFF_OUTS);
    unsigned* hist  = (unsigned*)(ws + OFF_HIST);
    unsigned* meta  = (unsigned*)(ws + OFF_META);
    unsigned long long* cand = (unsigned long long*)(ws + OFF_CAND);
    float* rwsh = (float*)(ws + OFF_RWSH);
    float* rwbr = (float*)(ws + OFF_RWBR);
    float* rwhd = (float*)(ws + OFF_RWHD);
    float* f_h1 = (float*)(ws + OFF_H1);     // 1 buffer (fallback) or 6 (fused)

    dim3 blk(256);

    hipMemsetAsync(hist, 0, (size_t)NBIN*4, stream);

    // ---- weight reorders ----
    reorder_w12_kernel<<<(196608+255)/256, blk, 0, stream>>>(W_sh, rwsh, 256, 196608);
    reorder_w12_kernel<<<(294912+255)/256, blk, 0, stream>>>(W1s,  rwbr,  64, 294912);
    reorder_wh_kernel<<<(10368+255)/256,  blk, 0, stream>>>(W2s, rwhd, 10368);

    // ---- shared conv: grid 12x47x2 (z = oc half) ----
    convb_kernel<256><<<dim3(12,47,2), blk, 0, stream>>>(x, rwsh, bn_sh, f_shared);

    if (fused) {
        // all 6 branch convs in one launch: z = branch*2 + half
        convb_kernel<64><<<dim3(12,47,12), blk, 0, stream>>>(f_shared, rwbr, bn1s, f_h1);
        // all 6 heads in one launch: z = branch (hm head also histograms)
        head3_kernel<<<dim3(12,24,6), blk, 0, stream>>>(
            f_h1, (size_t)64*HWSZ, 0, rwhd, b2s, f_outs, hist);
    } else {
        for (int i = 0; i < 6; i++) {
            convb_kernel<64><<<dim3(12,47,2), blk, 0, stream>>>(
                f_shared, rwbr + (size_t)i*49152, bn1s + (size_t)i*256, f_h1);
            head3_kernel<<<dim3(12,24,1), blk, 0, stream>>>(
                f_h1, 0, i, rwhd, b2s, f_outs, hist);
        }
    }

    // ---- top-k select + decode ----
    scan_kernel<<<1, 1024, 0, stream>>>(hist, meta);
    dim3 gscan((NSC + 255)/256);
    collect_kernel<<<gscan, blk, 0, stream>>>(f_outs, meta, cand);
    topk_decode_kernel<<<1, 512, SORT_M*sizeof(unsigned long long), stream>>>(
        meta, cand, f_outs, dout);

    (void)in_sizes; (void)n_in; (void)out_size;
}

// Round 6
// 1891.125 us; speedup vs baseline: 2.4204x; 1.0031x over previous
//
#include <hip/hip_runtime.h>
#include <math.h>

#define HH 376
#define WW 376
#define HWSZ (HH*WW)          // 141376
#define NSC (3*HWSZ)          // 424128
#define KTOP 500
#define CAND_CAP 65536
#define SORT_M 4096
#define NBIN 65536

// conv2 tiling: 64x4 px tile, 256 threads, thread = 2col x 2row x 8oc.
// blockIdx.z = br*2 + half (32 ocs per block).
#define CICB 4
#define CSINW 66
#define CSINH 6

// head tiling: 32x16 px tile, 256 threads, ICB 4
#define H2_ICB 4
#define H2_SINH 18
#define H2_SINW 34
#define H2_NLOAD (H2_ICB*H2_SINH*H2_SINW)  // 2448

__device__ __constant__ int d_pb[6] = {0, 3, 5, 6, 9, 11};
__device__ __constant__ int d_nc[6] = {3, 2, 1, 3, 2, 1};

// ---------------------------------------------------------------------------
// Weight reorder -> ic-major [b][IC][64][12] (9 real + 3 pad); offset for
// (ic,oc) = ic*768 + oc*12, wave-uniform in the conv kernel (scalar loads).
// ---------------------------------------------------------------------------
__global__ void reorder_w12_kernel(const float* __restrict__ src, float* __restrict__ dst,
                                   int IC, int total)
{
    int i = blockIdx.x*256 + threadIdx.x;
    if (i >= total) return;
    int per = IC*64*12;
    int b  = i / per;
    int r  = i - b*per;
    int ic = r / 768;
    int r3 = r - ic*768;
    int oc = r3 / 12;
    int k  = r3 - oc*12;
    float v = 0.f;
    if (k < 9)
        v = src[(size_t)b*64*IC*9 + ((size_t)oc*IC + ic)*9 + k];
    dst[i] = v;
}

// head weight reorder: ic-major [b][64][3][9]; offset ic*27 + o*9 uniform.
__global__ void reorder_wh_kernel(const float* __restrict__ src, float* __restrict__ dst,
                                  int total)
{
    int i = blockIdx.x*256 + threadIdx.x;
    if (i >= total) return;
    int per = 3*64*9;
    int b = i / per;
    int j = i - b*per;
    int ic = j / 27;
    int rr = j - ic*27;
    int oc = rr / 9;
    int kk = rr - oc*9;
    dst[i] = src[b*per + (oc*64 + ic)*9 + kk];
}

// ---------------------------------------------------------------------------
// conv2: 3x3 SAME conv, IC -> 64 oc (32 per block), BN+ReLU. 256-thread
// block, 64x4 tile. Thread = 2 cols x 2 rows x 8 ocs (32 acc).
// Wave-uniform oc group -> weights via SCALAR loads. LDS input reads are
// float2 (8 ds_read_b64 / ic vs 18 b32 before); staging = 3 float2 body
// loads + 1 halo scalar with offsets precomputed once (+= icadv per chunk).
// Accumulation order identical to rounds 2-5 (ic asc, w0..w8 chain) --
// required for bit-stable top-k ordering (absmax 0.0).
// ---------------------------------------------------------------------------
template<int IC>
__global__ __launch_bounds__(256,4) void conv2_kernel(
    const float* __restrict__ in,    // [IC][H][W]
    const float* __restrict__ rw,    // [br][IC][64][12]
    const float* __restrict__ bn,    // [br][4][64]
    float* __restrict__ out)         // [br][64][H][W]
{
    __shared__ float s_in[CICB][CSINH][CSINW];

    const int tid  = threadIdx.x;
    const int x0   = blockIdx.x * 64;
    const int y0   = blockIdx.y * 4;
    const int br   = blockIdx.z >> 1;
    const int half = blockIdx.z & 1;
    const int lx   = tid & 31;          // col pair (2lx, 2lx+1)
    const int rh   = (tid >> 5) & 1;    // rows rh*2, rh*2+1
    const int uslot = __builtin_amdgcn_readfirstlane(tid >> 6);  // 0..3

    const float* rwb = rw + (size_t)br * IC * 768;
    const float* bnb = bn + br * 256;
    float* outb = out + (size_t)br * 64 * HWSZ;

    float acc[8][4];                    // [oc][j*2+c]
#pragma unroll
    for (int o = 0; o < 8; o++)
#pragma unroll
        for (int jc = 0; jc < 4; jc++) acc[o][jc] = 0.f;

    // ---- staging plan (precomputed once) ----
    // body: 4ic x 6r x 32 col-pairs = 768 float2, 3 slots x 256 threads
    int boff[3]; bool bval[3]; int bsidx[3];
#pragma unroll
    for (int k = 0; k < 3; k++) {
        int idx = tid + k*256;
        int ic  = idx / 192;            // 6*32 per ic
        int rem = idx - ic*192;
        int r   = rem >> 5;
        int c2  = rem & 31;
        int gy  = y0 + r - 1;
        int gx  = x0 + 2*c2;
        bval[k] = (gy >= 0) && (gy < HH) && (gx + 1 < WW);
        boff[k] = ic*HWSZ + gy*WW + gx;
        bsidx[k]= ic*(CSINH*CSINW) + r*CSINW + 1 + 2*c2;
    }
    // halo: 4ic x 6r x 2 sides = 48 scalars
    bool hv = false; int hoff = 0, hsidx = 0;
    if (tid < 48) {
        int side = tid & 1;
        int e    = tid >> 1;            // 0..23
        int ic   = e / 6;
        int r    = e - ic*6;
        int gy   = y0 + r - 1;
        int gx   = side ? (x0 + 64) : (x0 - 1);
        hv    = (gy >= 0) && (gy < HH) && (gx >= 0) && (gx < WW);
        hoff  = ic*HWSZ + gy*WW + gx;
        hsidx = ic*(CSINH*CSINW) + r*CSINW + (side ? 65 : 0);
    }

    float2 pf[3]; float hpf = 0.f;
    int icadv = 0;
    auto do_prefetch = [&]() {
#pragma unroll
        for (int k = 0; k < 3; k++) {
            float2 z; z.x = 0.f; z.y = 0.f;
            pf[k] = bval[k] ? *(const float2*)(in + boff[k] + icadv) : z;
        }
        hpf = hv ? in[hoff + icadv] : 0.f;
    };
    do_prefetch();

    float* flat = &s_in[0][0][0];

    for (int ic0 = 0; ic0 < IC; ic0 += CICB) {
        __syncthreads();                       // previous compute done
#pragma unroll
        for (int k = 0; k < 3; k++) {
            flat[bsidx[k]]   = pf[k].x;
            flat[bsidx[k]+1] = pf[k].y;
        }
        if (tid < 48) flat[hsidx] = hpf;
        __syncthreads();
        if (ic0 + CICB < IC) { icadv += CICB*HWSZ; do_prefetch(); }

#pragma unroll 1
        for (int ic = 0; ic < CICB; ic++) {
            float vin[4][4];
#pragma unroll
            for (int r = 0; r < 4; r++) {
                float2 a = *(const float2*)&s_in[ic][rh*2 + r][2*lx];
                float2 b = *(const float2*)&s_in[ic][rh*2 + r][2*lx + 2];
                vin[r][0] = a.x; vin[r][1] = a.y; vin[r][2] = b.x; vin[r][3] = b.y;
            }
            // wave-uniform weight base: 8 ocs x 12 floats
            const float* wic = rwb + (size_t)(ic0 + ic)*768 + half*384 + uslot*96;
#pragma unroll
            for (int o = 0; o < 8; o++) {
                const float* wp = wic + o*12;
                float w0=wp[0],w1=wp[1],w2=wp[2],w3=wp[3],w4=wp[4],
                      w5=wp[5],w6=wp[6],w7=wp[7],w8=wp[8];
#pragma unroll
                for (int j = 0; j < 2; j++) {
#pragma unroll
                    for (int c = 0; c < 2; c++) {
                        float s = acc[o][j*2+c];
                        s = fmaf(w0, vin[j  ][c  ], s);
                        s = fmaf(w1, vin[j  ][c+1], s);
                        s = fmaf(w2, vin[j  ][c+2], s);
                        s = fmaf(w3, vin[j+1][c  ], s);
                        s = fmaf(w4, vin[j+1][c+1], s);
                        s = fmaf(w5, vin[j+1][c+2], s);
                        s = fmaf(w6, vin[j+2][c  ], s);
                        s = fmaf(w7, vin[j+2][c+1], s);
                        s = fmaf(w8, vin[j+2][c+2], s);
                        acc[o][j*2+c] = s;
                    }
                }
            }
        }
    }

    // ---- epilogue: BN + ReLU, float2 stores ----
    const int gx = x0 + 2*lx;
    if (gx < WW) {                       // gx even -> pair (gx, gx+1) in range
#pragma unroll
        for (int o = 0; o < 8; o++) {
            int oc = half*32 + uslot*8 + o;
            float g = bnb[oc], b = bnb[64+oc], m = bnb[128+oc], v = bnb[192+oc];
            float sc = g * rsqrtf(v + 1e-5f);
            float sh = b - m * sc;
#pragma unroll
            for (int j = 0; j < 2; j++) {
                int gy = y0 + rh*2 + j;  // 94*4 = 376 exact, no guard
                float2 val;
                val.x = fmaxf(fmaf(acc[o][j*2+0], sc, sh), 0.f);
                val.y = fmaxf(fmaf(acc[o][j*2+1], sc, sh), 0.f);
                *(float2*)&outb[(size_t)oc*HWSZ + (size_t)gy*WW + gx] = val;
            }
        }
    }
}

// ---------------------------------------------------------------------------
// head3: 3x3 conv 64 -> nch (<=3) + bias. 256 threads, 32x16 tile, ICB=4.
// Branch = br_base + blockIdx.z; weights thread-invariant -> scalar loads.
// The hm branch (br==0) also histograms its sigmoid scores.
// ---------------------------------------------------------------------------
__global__ __launch_bounds__(256) void head3_kernel(
    const float* __restrict__ in_base,
    size_t in_br_stride,
    int br_base,
    const float* __restrict__ rwh_all,   // [6][64][3][9]
    const float* __restrict__ bias_all,  // [6][3]
    float* __restrict__ outs,            // 12 planes
    unsigned* __restrict__ hist)
{
    __shared__ float s_in[H2_ICB][H2_SINH][H2_SINW];

    const int br  = br_base + blockIdx.z;
    const float* in = in_base + (size_t)blockIdx.z * in_br_stride;
    const float* rwh = rwh_all + (size_t)br * 1728;
    const float* bias = bias_all + br * 3;
    float* out = outs + (size_t)d_pb[br] * HWSZ;
    const int nch = d_nc[br];

    const int tid = threadIdx.x;
    const int x0  = blockIdx.x * 32;
    const int y0  = blockIdx.y * 16;
    const int col = tid & 31;
    const int rs  = tid >> 5;            // rows 2rs, 2rs+1

    float acc[3][2];
#pragma unroll
    for (int o = 0; o < 3; o++) { acc[o][0] = 0.f; acc[o][1] = 0.f; }

    int offs[10];
    bool val[10];
#pragma unroll
    for (int k = 0; k < 10; k++) {
        int idx = tid + k*256;
        int ic  = idx / (H2_SINH*H2_SINW);
        int rem = idx - ic*(H2_SINH*H2_SINW);
        int r   = rem / H2_SINW;
        int c   = rem - r*H2_SINW;
        int gy  = y0 + r - 1;
        int gx  = x0 + c - 1;
        val[k]  = (idx < H2_NLOAD) && (gy >= 0) && (gy < HH) && (gx >= 0) && (gx < WW);
        offs[k] = ic*HWSZ + gy*WW + gx;
    }
    float pf[10];
    int icadv = 0;
    auto do_prefetch = [&]() {
#pragma unroll
        for (int k = 0; k < 10; k++)
            pf[k] = val[k] ? in[offs[k] + icadv] : 0.f;
    };
    do_prefetch();

    float* flat = &s_in[0][0][0];

    for (int ic0 = 0; ic0 < 64; ic0 += H2_ICB) {
        __syncthreads();
#pragma unroll
        for (int k = 0; k < 9; k++) flat[tid + k*256] = pf[k];
        if (tid < H2_NLOAD - 9*256) flat[tid + 9*256] = pf[9];
        __syncthreads();
        if (ic0 + H2_ICB < 64) { icadv += H2_ICB*HWSZ; do_prefetch(); }

#pragma unroll 1
        for (int ic = 0; ic < H2_ICB; ic++) {
            float vin[4][3];
#pragma unroll
            for (int r = 0; r < 4; r++) {
                vin[r][0] = s_in[ic][2*rs + r][col];
                vin[r][1] = s_in[ic][2*rs + r][col+1];
                vin[r][2] = s_in[ic][2*rs + r][col+2];
            }
            const float* wic = rwh + (ic0 + ic)*27;   // thread-invariant
#pragma unroll
            for (int o = 0; o < 3; o++) {
                const float* wp = wic + o*9;
                float w0=wp[0],w1=wp[1],w2=wp[2],w3=wp[3],w4=wp[4],
                      w5=wp[5],w6=wp[6],w7=wp[7],w8=wp[8];
#pragma unroll
                for (int j = 0; j < 2; j++) {
                    float s = acc[o][j];
                    s = fmaf(w0, vin[j  ][0], s);
                    s = fmaf(w1, vin[j  ][1], s);
                    s = fmaf(w2, vin[j  ][2], s);
                    s = fmaf(w3, vin[j+1][0], s);
                    s = fmaf(w4, vin[j+1][1], s);
                    s = fmaf(w5, vin[j+1][2], s);
                    s = fmaf(w6, vin[j+2][0], s);
                    s = fmaf(w7, vin[j+2][1], s);
                    s = fmaf(w8, vin[j+2][2], s);
                    acc[o][j] = s;
                }
            }
        }
    }

    const int gx = x0 + col;
    if (gx < WW) {
#pragma unroll
        for (int o = 0; o < 3; o++) {
            if (o < nch) {
                float bo = bias[o];
#pragma unroll
                for (int j = 0; j < 2; j++) {
                    int gy = y0 + 2*rs + j;
                    if (gy < HH) {
                        float v = acc[o][j] + bo;
                        out[(size_t)o*HWSZ + (size_t)gy*WW + gx] = v;
                        if (br == 0) {   // hm branch: histogram sigmoid bits
                            float sc = 1.f / (1.f + expf(-v));
                            atomicAdd(&hist[__float_as_uint(sc) >> 16], 1u);
                        }
                    }
                }
            }
        }
    }
}

// ---------------------------------------------------------------------------
// Top-K: histogram (in head3) -> threshold-bucket scan -> collect -> sort.
// ---------------------------------------------------------------------------
__global__ void scan_kernel(const unsigned* __restrict__ hist, unsigned* __restrict__ meta)
{
    __shared__ unsigned part[1024];
    __shared__ unsigned scn[1024];
    __shared__ int tcs;
    const int t = threadIdx.x;
    unsigned ssum = 0;
    for (int b = t*64; b < t*64 + 64; b++) ssum += hist[b];
    part[t] = ssum;
    scn[t] = ssum;
    __syncthreads();
    for (int off = 1; off < 1024; off <<= 1) {
        unsigned v = (t + off < 1024) ? scn[t + off] : 0u;
        __syncthreads();
        scn[t] += v;
        __syncthreads();
    }
    unsigned sufEx = scn[t] - part[t];
    if (sufEx < KTOP && scn[t] >= KTOP) tcs = t;
    __syncthreads();
    if (t == 0) {
        int tc = tcs;
        unsigned c = scn[tc] - part[tc];
        unsigned B = tc * 64;
        for (int b = tc*64 + 63; b >= tc*64; b--) {
            c += hist[b];
            if (c >= KTOP) { B = (unsigned)b; break; }
        }
        meta[0] = B;
        meta[1] = 0;
    }
}

__global__ void collect_kernel(const float* __restrict__ hm,
                               unsigned* __restrict__ meta,
                               unsigned long long* __restrict__ cand)
{
    int i = blockIdx.x * 256 + threadIdx.x;
    if (i >= NSC) return;
    float sc = 1.f / (1.f + expf(-hm[i]));
    unsigned key = __float_as_uint(sc);
    if ((key >> 16) >= meta[0]) {
        unsigned pos = atomicAdd(&meta[1], 1u);
        if (pos < CAND_CAP)
            cand[pos] = ((unsigned long long)key << 32) | (unsigned)(0xFFFFFFFFu - (unsigned)i);
    }
}

__global__ void topk_decode_kernel(const unsigned* __restrict__ meta,
                                   const unsigned long long* __restrict__ cand,
                                   const float* __restrict__ P,
                                   float* __restrict__ dout)
{
    extern __shared__ unsigned long long s[];
    __shared__ unsigned long long red[512];
    const int t = threadIdx.x;
    unsigned n = meta[1];
    if (n > CAND_CAP) n = CAND_CAP;

    if (n <= SORT_M) {
        unsigned m = 1024;
        while (m < n) m <<= 1;
        for (unsigned i = t; i < m; i += 512) s[i] = (i < n) ? cand[i] : 0ULL;
        __syncthreads();
        for (unsigned k = 2; k <= m; k <<= 1) {
            for (unsigned j = k >> 1; j > 0; j >>= 1) {
                for (unsigned i = t; i < m; i += 512) {
                    unsigned ixj = i ^ j;
                    if (ixj > i) {
                        unsigned long long a = s[i], b = s[ixj];
                        bool desc = ((i & k) == 0);
                        if (desc ? (a < b) : (a > b)) { s[i] = b; s[ixj] = a; }
                    }
                }
                __syncthreads();
            }
        }
    } else {
        unsigned long long last = 0xFFFFFFFFFFFFFFFFULL;
        for (int slot = 0; slot < KTOP; slot++) {
            unsigned long long best = 0;
            for (unsigned i = t; i < n; i += 512) {
                unsigned long long v = cand[i];
                if (v < last && v > best) best = v;
            }
            red[t] = best;
            __syncthreads();
            for (int off = 256; off > 0; off >>= 1) {
                if (t < off) { if (red[t+off] > red[t]) red[t] = red[t+off]; }
                __syncthreads();
            }
            if (t == 0) s[slot] = red[0];
            last = red[0];
            __syncthreads();
        }
    }
    __syncthreads();

    if (t < KTOP) {
        unsigned long long e = s[t];
        unsigned key = (unsigned)(e >> 32);
        unsigned idx = 0xFFFFFFFFu - (unsigned)(e & 0xFFFFFFFFu);
        int cls = (int)(idx / HWSZ);
        int sp  = (int)(idx % HWSZ);
        float ys = (float)(sp / WW);
        float xs = (float)(sp % WW);
        float shm = __uint_as_float(key);

        float ct0 = P[3*HWSZ + sp], ct1 = P[4*HWSZ + sp];
        float cz  = P[5*HWSZ + sp];
        float d0  = expf(P[6*HWSZ + sp]);
        float d1  = expf(P[7*HWSZ + sp]);
        float d2  = expf(P[8*HWSZ + sp]);
        float r0  = P[9*HWSZ + sp], r1 = P[10*HWSZ + sp];
        float iou = P[11*HWSZ + sp];

        float xg = (xs + ct0) * 4.0f * 0.1f + (-75.2f);
        float yg = (ys + ct1) * 4.0f * 0.1f + (-75.2f);
        float heading = atan2f(r1, r0);
        iou = (iou + 1.f) * 0.5f;
        iou = fminf(fmaxf(iou, 0.f), 1.f);
        const float RECT[3] = {0.68f, 0.71f, 0.65f};
        float r = RECT[cls];
        float score = powf(shm, 1.f - r) * powf(iou, r);
        score = (score > 0.1f) ? score : 0.f;

        dout[t*7+0] = xg;  dout[t*7+1] = yg;  dout[t*7+2] = cz;
        dout[t*7+3] = d0;  dout[t*7+4] = d1;  dout[t*7+5] = d2;
        dout[t*7+6] = heading;
        dout[3500 + t] = score;
        dout[4000 + t] = (float)cls;
    }
}

// ---------------------------------------------------------------------------
extern "C" void kernel_launch(void* const* d_in, const int* in_sizes, int n_in,
                              void* d_out, int out_size, void* d_ws, size_t ws_size,
                              hipStream_t stream)
{
    const float* x    = (const float*)d_in[0];   // [256][376][376]
    const float* W_sh = (const float*)d_in[1];   // [64][256][9]
    const float* bn_sh= (const float*)d_in[2];   // [4][64]
    const float* W1s  = (const float*)d_in[3];   // [6][64][64][9]
    const float* bn1s = (const float*)d_in[4];   // [6][4][64]
    const float* W2s  = (const float*)d_in[5];   // [6][3][64][9]
    const float* b2s  = (const float*)d_in[6];   // [6][3]
    float* dout = (float*)d_out;

    char* ws = (char*)d_ws;
    const size_t SHARED_B = (size_t)64*HWSZ*4;            // 36,192,256
    const size_t OFF_SHARED = 0;
    const size_t OFF_OUTS   = OFF_SHARED + SHARED_B;
    const size_t OFF_HIST   = OFF_OUTS   + (size_t)12*HWSZ*4;
    const size_t OFF_META   = OFF_HIST   + (size_t)NBIN*4;
    const size_t OFF_CAND   = OFF_META   + 256;
    const size_t OFF_RWSH   = OFF_CAND   + (size_t)CAND_CAP*8;
    const size_t OFF_RWBR   = OFF_RWSH   + (size_t)196608*4;
    const size_t OFF_RWHD   = OFF_RWBR   + (size_t)294912*4;
    const size_t OFF_H1     = OFF_RWHD   + (size_t)10368*4;
    const size_t NEED_FUSED = OFF_H1 + 6*SHARED_B;        // ~263 MB
    const bool fused = (ws_size >= NEED_FUSED);

    float* f_shared = (float*)(ws + OFF_SHARED);
    float* f_outs   = (float*)(ws + OFF_OUTS);
    unsigned* hist  = (unsigned*)(ws + OFF_HIST);
    unsigned* meta  = (unsigned*)(ws + OFF_META);
    unsigned long long* cand = (unsigned long long*)(ws + OFF_CAND);
    float* rwsh = (float*)(ws + OFF_RWSH);
    float* rwbr = (float*)(ws + OFF_RWBR);
    float* rwhd = (float*)(ws + OFF_RWHD);
    float* f_h1 = (float*)(ws + OFF_H1);

    dim3 blk(256);

    hipMemsetAsync(hist, 0, (size_t)NBIN*4, stream);

    // ---- weight reorders ----
    reorder_w12_kernel<<<(196608+255)/256, blk, 0, stream>>>(W_sh, rwsh, 256, 196608);
    reorder_w12_kernel<<<(294912+255)/256, blk, 0, stream>>>(W1s,  rwbr,  64, 294912);
    reorder_wh_kernel<<<(10368+255)/256,  blk, 0, stream>>>(W2s, rwhd, 10368);

    // ---- shared conv: grid 6x94x2 (z = oc half) ----
    conv2_kernel<256><<<dim3(6,94,2), blk, 0, stream>>>(x, rwsh, bn_sh, f_shared);

    if (fused) {
        conv2_kernel<64><<<dim3(6,94,12), blk, 0, stream>>>(f_shared, rwbr, bn1s, f_h1);
        head3_kernel<<<dim3(12,24,6), blk, 0, stream>>>(
            f_h1, (size_t)64*HWSZ, 0, rwhd, b2s, f_outs, hist);
    } else {
        for (int i = 0; i < 6; i++) {
            conv2_kernel<64><<<dim3(6,94,2), blk, 0, stream>>>(
                f_shared, rwbr + (size_t)i*49152, bn1s + (size_t)i*256, f_h1);
            head3_kernel<<<dim3(12,24,1), blk, 0, stream>>>(
                f_h1, 0, i, rwhd, b2s, f_outs, hist);
        }
    }

    // ---- top-k select + decode ----
    scan_kernel<<<1, 1024, 0, stream>>>(hist, meta);
    dim3 gscan((NSC + 255)/256);
    collect_kernel<<<gscan, blk, 0, stream>>>(f_outs, meta, cand);
    topk_decode_kernel<<<1, 512, SORT_M*sizeof(unsigned long long), stream>>>(
        meta, cand, f_outs, dout);

    (void)in_sizes; (void)n_in; (void)out_size;
}

// Round 7
// 1400.034 us; speedup vs baseline: 3.2694x; 1.3508x over previous
//
#include <hip/hip_runtime.h>
#include <math.h>

#define HH 376
#define WW 376
#define HWSZ (HH*WW)          // 141376
#define NSC (3*HWSZ)          // 424128
#define KTOP 500
#define CAND_CAP 65536
#define SORT_M 4096
#define NBIN 65536

// convb tiling: 32x8 px tile, 256 threads (4 waves), wave = 8 ocs,
// block handles 32 ocs (blockIdx.z parity selects which half).
#define CICB 4
#define CSINW 34
#define CSINH 10
#define CNLOAD (CICB*CSINH*CSINW)   // 1360

// head tiling: 32x16 px tile, 256 threads, ICB 4
#define H2_ICB 4
#define H2_SINH 18
#define H2_SINW 34
#define H2_NLOAD (H2_ICB*H2_SINH*H2_SINW)  // 2448

__device__ __constant__ int d_pb[6] = {0, 3, 5, 6, 9, 11};
__device__ __constant__ int d_nc[6] = {3, 2, 1, 3, 2, 1};
__device__ __constant__ int d_goff[6] = {0, 0, 2, 3, 6, 8};  // g-slot base per branch

// ---------------------------------------------------------------------------
// Weight reorder -> ic-major [b][IC][64][12] (9 real + 3 pad); offset for
// (ic,oc) = ic*768 + oc*12. Wave-uniform in convb (scalar loads); 16B-aligned
// rows for branchpx float4 loads.
// ---------------------------------------------------------------------------
__global__ void reorder_w12_kernel(const float* __restrict__ src, float* __restrict__ dst,
                                   int IC, int total)
{
    int i = blockIdx.x*256 + threadIdx.x;
    if (i >= total) return;
    int per = IC*64*12;
    int b  = i / per;
    int r  = i - b*per;
    int ic = r / 768;
    int r3 = r - ic*768;
    int oc = r3 / 12;
    int k  = r3 - oc*12;
    float v = 0.f;
    if (k < 9)
        v = src[(size_t)b*64*IC*9 + ((size_t)oc*IC + ic)*9 + k];
    dst[i] = v;
}

// head weight reorder: ic-major [b][64][3][9]; offset ic*27 + o*9.
__global__ void reorder_wh_kernel(const float* __restrict__ src, float* __restrict__ dst,
                                  int total)
{
    int i = blockIdx.x*256 + threadIdx.x;
    if (i >= total) return;
    int per = 3*64*9;
    int b = i / per;
    int j = i - b*per;
    int ic = j / 27;
    int rr = j - ic*27;
    int oc = rr / 9;
    int kk = rr - oc*9;
    dst[i] = src[b*per + (oc*64 + ic)*9 + kk];
}

// ---------------------------------------------------------------------------
// convb (round-5 proven kernel, conflict-free): 3x3 SAME conv, IC -> 64 oc
// (32 per block), BN+ReLU. Wave-uniform oc group -> scalar weight loads.
// Accumulation order (ic asc, w0..w8 chain) is bit-stable vs np reference --
// REQUIRED on the hm path (top-k ordering).
// ---------------------------------------------------------------------------
template<int IC>
__global__ __launch_bounds__(256) void convb_kernel(
    const float* __restrict__ in,    // [IC][H][W]
    const float* __restrict__ rw,    // [br][IC][64][12]
    const float* __restrict__ bn,    // [br][4][64]
    float* __restrict__ out)         // [br][64][H][W]
{
    __shared__ float s_in[CICB][CSINH][CSINW];

    const int tid  = threadIdx.x;
    const int x0   = blockIdx.x * 32;
    const int y0   = blockIdx.y * 8;
    const int br   = blockIdx.z >> 1;
    const int half = blockIdx.z & 1;
    const int col  = tid & 31;
    const int rh   = (tid >> 5) & 1;
    const int uslot = __builtin_amdgcn_readfirstlane(tid >> 6);  // 0..3

    const float* rwb = rw + (size_t)br * IC * 768;
    const float* bnb = bn + br * 256;
    float* outb = out + (size_t)br * 64 * HWSZ;

    float acc[8][4];
#pragma unroll
    for (int o = 0; o < 8; o++)
#pragma unroll
        for (int j = 0; j < 4; j++) acc[o][j] = 0.f;

    float pf[6];
    int icbase = 0;
    auto do_prefetch = [&]() {
#pragma unroll
        for (int k = 0; k < 6; k++) {
            int idx = tid + k*256;
            int ic  = idx / 340;
            int rem = idx - ic*340;
            int r   = rem / 34;
            int c   = rem - r*34;
            int gy  = y0 + r - 1;
            int gx  = x0 + c - 1;
            bool v  = (idx < CNLOAD) && (gy >= 0) && (gy < HH) && (gx >= 0) && (gx < WW);
            pf[k] = v ? in[(size_t)(icbase+ic)*HWSZ + gy*WW + gx] : 0.f;
        }
    };
    do_prefetch();

    float* flat = &s_in[0][0][0];

    for (int ic0 = 0; ic0 < IC; ic0 += CICB) {
        __syncthreads();
#pragma unroll
        for (int k = 0; k < 5; k++) flat[tid + k*256] = pf[k];
        if (tid < CNLOAD - 5*256) flat[tid + 5*256] = pf[5];
        __syncthreads();
        if (ic0 + CICB < IC) { icbase = ic0 + CICB; do_prefetch(); }

#pragma unroll 1
        for (int ic = 0; ic < CICB; ic++) {
            float vin[6][3];
#pragma unroll
            for (int r = 0; r < 6; r++) {
                vin[r][0] = s_in[ic][rh*4 + r][col];
                vin[r][1] = s_in[ic][rh*4 + r][col+1];
                vin[r][2] = s_in[ic][rh*4 + r][col+2];
            }
            const float* wic = rwb + (size_t)(ic0 + ic)*768 + half*384 + uslot*96;
#pragma unroll
            for (int o = 0; o < 8; o++) {
                const float* wp = wic + o*12;
                float w0=wp[0],w1=wp[1],w2=wp[2],w3=wp[3],w4=wp[4],
                      w5=wp[5],w6=wp[6],w7=wp[7],w8=wp[8];
#pragma unroll
                for (int j = 0; j < 4; j++) {
                    float s = acc[o][j];
                    s = fmaf(w0, vin[j  ][0], s);
                    s = fmaf(w1, vin[j  ][1], s);
                    s = fmaf(w2, vin[j  ][2], s);
                    s = fmaf(w3, vin[j+1][0], s);
                    s = fmaf(w4, vin[j+1][1], s);
                    s = fmaf(w5, vin[j+1][2], s);
                    s = fmaf(w6, vin[j+2][0], s);
                    s = fmaf(w7, vin[j+2][1], s);
                    s = fmaf(w8, vin[j+2][2], s);
                    acc[o][j] = s;
                }
            }
        }
    }

    const int gx = x0 + col;
    if (gx < WW) {
#pragma unroll
        for (int o = 0; o < 8; o++) {
            int oc = half*32 + uslot*8 + o;
            float g = bnb[oc], b = bnb[64+oc], m = bnb[128+oc], v = bnb[192+oc];
            float sc = g * rsqrtf(v + 1e-5f);
            float sh = b - m * sc;
#pragma unroll
            for (int j = 0; j < 4; j++) {
                int gy = y0 + rh*4 + j;
                float valo = fmaxf(fmaf(acc[o][j], sc, sh), 0.f);
                outb[(size_t)oc*HWSZ + (size_t)gy*WW + gx] = valo;
            }
        }
    }
}

// ---------------------------------------------------------------------------
// head3 (hm only now): 3x3 conv 64 -> 3 + bias; also histograms sigmoid bits.
// Bit-exact chain preserved.
// ---------------------------------------------------------------------------
__global__ __launch_bounds__(256) void head3_kernel(
    const float* __restrict__ in,        // [64][H][W]  (hm h1)
    const float* __restrict__ rwh_all,   // [6][64][3][9]
    const float* __restrict__ bias_all,  // [6][3]
    float* __restrict__ outs,            // 3 hm planes
    unsigned* __restrict__ hist)
{
    __shared__ float s_in[H2_ICB][H2_SINH][H2_SINW];

    const float* rwh = rwh_all;          // branch 0
    const float* bias = bias_all;

    const int tid = threadIdx.x;
    const int x0  = blockIdx.x * 32;
    const int y0  = blockIdx.y * 16;
    const int col = tid & 31;
    const int rs  = tid >> 5;

    float acc[3][2];
#pragma unroll
    for (int o = 0; o < 3; o++) { acc[o][0] = 0.f; acc[o][1] = 0.f; }

    int offs[10];
    bool val[10];
#pragma unroll
    for (int k = 0; k < 10; k++) {
        int idx = tid + k*256;
        int ic  = idx / (H2_SINH*H2_SINW);
        int rem = idx - ic*(H2_SINH*H2_SINW);
        int r   = rem / H2_SINW;
        int c   = rem - r*H2_SINW;
        int gy  = y0 + r - 1;
        int gx  = x0 + c - 1;
        val[k]  = (idx < H2_NLOAD) && (gy >= 0) && (gy < HH) && (gx >= 0) && (gx < WW);
        offs[k] = ic*HWSZ + gy*WW + gx;
    }
    float pf[10];
    int icadv = 0;
    auto do_prefetch = [&]() {
#pragma unroll
        for (int k = 0; k < 10; k++)
            pf[k] = val[k] ? in[offs[k] + icadv] : 0.f;
    };
    do_prefetch();

    float* flat = &s_in[0][0][0];

    for (int ic0 = 0; ic0 < 64; ic0 += H2_ICB) {
        __syncthreads();
#pragma unroll
        for (int k = 0; k < 9; k++) flat[tid + k*256] = pf[k];
        if (tid < H2_NLOAD - 9*256) flat[tid + 9*256] = pf[9];
        __syncthreads();
        if (ic0 + H2_ICB < 64) { icadv += H2_ICB*HWSZ; do_prefetch(); }

#pragma unroll 1
        for (int ic = 0; ic < H2_ICB; ic++) {
            float vin[4][3];
#pragma unroll
            for (int r = 0; r < 4; r++) {
                vin[r][0] = s_in[ic][2*rs + r][col];
                vin[r][1] = s_in[ic][2*rs + r][col+1];
                vin[r][2] = s_in[ic][2*rs + r][col+2];
            }
            const float* wic = rwh + (ic0 + ic)*27;
#pragma unroll
            for (int o = 0; o < 3; o++) {
                const float* wp = wic + o*9;
                float w0=wp[0],w1=wp[1],w2=wp[2],w3=wp[3],w4=wp[4],
                      w5=wp[5],w6=wp[6],w7=wp[7],w8=wp[8];
#pragma unroll
                for (int j = 0; j < 2; j++) {
                    float s = acc[o][j];
                    s = fmaf(w0, vin[j  ][0], s);
                    s = fmaf(w1, vin[j  ][1], s);
                    s = fmaf(w2, vin[j  ][2], s);
                    s = fmaf(w3, vin[j+1][0], s);
                    s = fmaf(w4, vin[j+1][1], s);
                    s = fmaf(w5, vin[j+1][2], s);
                    s = fmaf(w6, vin[j+2][0], s);
                    s = fmaf(w7, vin[j+2][1], s);
                    s = fmaf(w8, vin[j+2][2], s);
                    acc[o][j] = s;
                }
            }
        }
    }

    const int gx = x0 + col;
    if (gx < WW) {
#pragma unroll
        for (int o = 0; o < 3; o++) {
            float bo = bias[o];
#pragma unroll
            for (int j = 0; j < 2; j++) {
                int gy = y0 + 2*rs + j;
                if (gy < HH) {
                    float v = acc[o][j] + bo;
                    outs[(size_t)o*HWSZ + (size_t)gy*WW + gx] = v;
                    float sc = 1.f / (1.f + expf(-v));
                    atomicAdd(&hist[__float_as_uint(sc) >> 16], 1u);
                }
            }
        }
    }
}

// ---------------------------------------------------------------------------
// Top-K: hist (in head3) -> scan -> collect -> sort (writes sorted[500]).
// ---------------------------------------------------------------------------
__global__ void scan_kernel(const unsigned* __restrict__ hist, unsigned* __restrict__ meta)
{
    __shared__ unsigned part[1024];
    __shared__ unsigned scn[1024];
    __shared__ int tcs;
    const int t = threadIdx.x;
    unsigned ssum = 0;
    for (int b = t*64; b < t*64 + 64; b++) ssum += hist[b];
    part[t] = ssum;
    scn[t] = ssum;
    __syncthreads();
    for (int off = 1; off < 1024; off <<= 1) {
        unsigned v = (t + off < 1024) ? scn[t + off] : 0u;
        __syncthreads();
        scn[t] += v;
        __syncthreads();
    }
    unsigned sufEx = scn[t] - part[t];
    if (sufEx < KTOP && scn[t] >= KTOP) tcs = t;
    __syncthreads();
    if (t == 0) {
        int tc = tcs;
        unsigned c = scn[tc] - part[tc];
        unsigned B = tc * 64;
        for (int b = tc*64 + 63; b >= tc*64; b--) {
            c += hist[b];
            if (c >= KTOP) { B = (unsigned)b; break; }
        }
        meta[0] = B;
        meta[1] = 0;
    }
}

__global__ void collect_kernel(const float* __restrict__ hm,
                               unsigned* __restrict__ meta,
                               unsigned long long* __restrict__ cand)
{
    int i = blockIdx.x * 256 + threadIdx.x;
    if (i >= NSC) return;
    float sc = 1.f / (1.f + expf(-hm[i]));
    unsigned key = __float_as_uint(sc);
    if ((key >> 16) >= meta[0]) {
        unsigned pos = atomicAdd(&meta[1], 1u);
        if (pos < CAND_CAP)
            cand[pos] = ((unsigned long long)key << 32) | (unsigned)(0xFFFFFFFFu - (unsigned)i);
    }
}

__global__ void topk_sort_kernel(const unsigned* __restrict__ meta,
                                 const unsigned long long* __restrict__ cand,
                                 unsigned long long* __restrict__ sorted)
{
    extern __shared__ unsigned long long s[];
    __shared__ unsigned long long red[512];
    const int t = threadIdx.x;
    unsigned n = meta[1];
    if (n > CAND_CAP) n = CAND_CAP;

    if (n <= SORT_M) {
        unsigned m = 1024;
        while (m < n) m <<= 1;
        for (unsigned i = t; i < m; i += 512) s[i] = (i < n) ? cand[i] : 0ULL;
        __syncthreads();
        for (unsigned k = 2; k <= m; k <<= 1) {
            for (unsigned j = k >> 1; j > 0; j >>= 1) {
                for (unsigned i = t; i < m; i += 512) {
                    unsigned ixj = i ^ j;
                    if (ixj > i) {
                        unsigned long long a = s[i], b = s[ixj];
                        bool desc = ((i & k) == 0);
                        if (desc ? (a < b) : (a > b)) { s[i] = b; s[ixj] = a; }
                    }
                }
                __syncthreads();
            }
        }
    } else {
        unsigned long long last = 0xFFFFFFFFFFFFFFFFULL;
        for (int slot = 0; slot < KTOP; slot++) {
            unsigned long long best = 0;
            for (unsigned i = t; i < n; i += 512) {
                unsigned long long v = cand[i];
                if (v < last && v > best) best = v;
            }
            red[t] = best;
            __syncthreads();
            for (int off = 256; off > 0; off >>= 1) {
                if (t < off) { if (red[t+off] > red[t]) red[t] = red[t+off]; }
                __syncthreads();
            }
            if (t == 0) s[slot] = red[0];
            last = red[0];
            __syncthreads();
        }
    }
    __syncthreads();
    if (t < KTOP) sorted[t] = s[t];
}

// ---------------------------------------------------------------------------
// branchpx: evaluate branches 1..5 ONLY at the 500 selected pixels.
// Block = (slot, branch-1). Phase 1: h1 (64 oc) on the 3x3 neighborhood from
// the full-plane shared (5x5 window, zero-padded). Phase 2: head dot + bias.
// fp32 accumulation, order-free (only hm needs bit-exactness).
// ---------------------------------------------------------------------------
__global__ __launch_bounds__(256) void branchpx_kernel(
    const unsigned long long* __restrict__ sorted,   // [500]
    const float* __restrict__ fsh,                   // shared [64][H][W]
    const float* __restrict__ rwbr,                  // [6][64ic][64oc][12]
    const float* __restrict__ rwhd,                  // [6][64ic][3][9]
    const float* __restrict__ bn1s,                  // [6][4][64]
    const float* __restrict__ b2s,                   // [6][3]
    float* __restrict__ g)                           // [500][9]
{
    __shared__ float sh[64*28];          // [ic][25 pad 28]
    __shared__ float part[4*9*64];       // [icq][p][oc]
    __shared__ float h1s[9*64];          // [p][oc]
    __shared__ float red[3*64];          // [o][ic]

    const int slot = blockIdx.x;
    const int br   = 1 + blockIdx.y;     // 1..5
    const int tid  = threadIdx.x;

    unsigned long long e = sorted[slot];
    unsigned idx = 0xFFFFFFFFu - (unsigned)(e & 0xFFFFFFFFu);
    int sp = (int)(idx % HWSZ);
    int py = sp / WW, px = sp % WW;

    // ---- stage shared 5x5 x 64ic, zero-padded ----
    for (int ee = tid; ee < 1600; ee += 256) {
        int ic = ee / 25;
        int p  = ee - ic*25;
        int dy = p / 5, dx = p - dy*5;
        int gy = py + dy - 2, gx = px + dx - 2;
        float v = 0.f;
        if (gy >= 0 && gy < HH && gx >= 0 && gx < WW)
            v = fsh[(size_t)ic*HWSZ + gy*WW + gx];
        sh[ic*28 + p] = v;
    }
    __syncthreads();

    // ---- phase 1: partial h1 over ic quarter ----
    const int oc  = tid & 63;
    const int icq = tid >> 6;            // 0..3
    const float* rwblk = rwbr + (size_t)br*49152;   // [ic][oc][12]

    float acc[9];
#pragma unroll
    for (int p = 0; p < 9; p++) acc[p] = 0.f;

#pragma unroll 1
    for (int icl = 0; icl < 16; icl++) {
        int ic = icq*16 + icl;
        const float* wp = rwblk + (size_t)ic*768 + oc*12;
        float4 wA = *(const float4*)(wp);
        float4 wB = *(const float4*)(wp + 4);
        float w8 = wp[8];
        const float* srow = &sh[ic*28];
        float s_[25];
#pragma unroll
        for (int q = 0; q < 6; q++) {
            float4 v = *(const float4*)(srow + q*4);
            s_[q*4+0] = v.x; s_[q*4+1] = v.y; s_[q*4+2] = v.z; s_[q*4+3] = v.w;
        }
        s_[24] = srow[24];
#pragma unroll
        for (int ty = 0; ty < 3; ty++) {
#pragma unroll
            for (int tx = 0; tx < 3; tx++) {
                int p = ty*3 + tx;
                float s = acc[p];
                s = fmaf(wA.x, s_[(ty  )*5 + tx  ], s);
                s = fmaf(wA.y, s_[(ty  )*5 + tx+1], s);
                s = fmaf(wA.z, s_[(ty  )*5 + tx+2], s);
                s = fmaf(wA.w, s_[(ty+1)*5 + tx  ], s);
                s = fmaf(wB.x, s_[(ty+1)*5 + tx+1], s);
                s = fmaf(wB.y, s_[(ty+1)*5 + tx+2], s);
                s = fmaf(wB.z, s_[(ty+2)*5 + tx  ], s);
                s = fmaf(wB.w, s_[(ty+2)*5 + tx+1], s);
                s = fmaf(w8,   s_[(ty+2)*5 + tx+2], s);
                acc[p] = s;
            }
        }
    }
#pragma unroll
    for (int p = 0; p < 9; p++) part[(icq*9 + p)*64 + oc] = acc[p];
    __syncthreads();

    // ---- reduce + BN + ReLU + head-conv zero-pad ----
    const float* bnb = bn1s + br*256;
    for (int v = tid; v < 576; v += 256) {
        int p = v >> 6, o = v & 63;
        float x = part[(0*9+p)*64+o] + part[(1*9+p)*64+o]
                + part[(2*9+p)*64+o] + part[(3*9+p)*64+o];
        float gg = bnb[o], bb = bnb[64+o], mm = bnb[128+o], vv = bnb[192+o];
        float sc = gg * rsqrtf(vv + 1e-5f);
        float shf = bb - mm * sc;
        float h1v = fmaxf(fmaf(x, sc, shf), 0.f);
        int ty = p / 3 - 1, tx = p % 3 - 1;
        int gy = py + ty, gx = px + tx;
        if (gy < 0 || gy >= HH || gx < 0 || gx >= WW) h1v = 0.f;
        h1s[p*64 + o] = h1v;
    }
    __syncthreads();

    // ---- phase 2: head partials ----
    if (tid < 192) {
        int o = tid >> 6, ic = tid & 63;
        const float* wh = rwhd + (size_t)br*1728 + ic*27 + o*9;
        float s = 0.f;
#pragma unroll
        for (int k = 0; k < 9; k++) s = fmaf(wh[k], h1s[k*64 + ic], s);
        red[o*64 + ic] = s;
    }
    __syncthreads();

    if (tid < 3 && tid < d_nc[br]) {
        float s = b2s[br*3 + tid];
        for (int ic = 0; ic < 64; ic++) s += red[tid*64 + ic];
        g[slot*9 + d_goff[br] + tid] = s;
    }
}

// ---------------------------------------------------------------------------
// finish: assemble boxes/scores/cls from sorted keys + gathered g values.
// ---------------------------------------------------------------------------
__global__ void finish_kernel(const unsigned long long* __restrict__ sorted,
                              const float* __restrict__ g,
                              float* __restrict__ dout)
{
    int t = blockIdx.x*256 + threadIdx.x;
    if (t >= KTOP) return;
    unsigned long long e = sorted[t];
    unsigned key = (unsigned)(e >> 32);
    unsigned idx = 0xFFFFFFFFu - (unsigned)(e & 0xFFFFFFFFu);
    int cls = (int)(idx / HWSZ);
    int sp  = (int)(idx % HWSZ);
    float ys = (float)(sp / WW);
    float xs = (float)(sp % WW);
    float shm = __uint_as_float(key);

    const float* gg = g + t*9;
    float ct0 = gg[0], ct1 = gg[1], cz = gg[2];
    float d0 = expf(gg[3]), d1 = expf(gg[4]), d2 = expf(gg[5]);
    float r0 = gg[6], r1 = gg[7], iou = gg[8];

    float xg = (xs + ct0) * 4.0f * 0.1f + (-75.2f);
    float yg = (ys + ct1) * 4.0f * 0.1f + (-75.2f);
    float heading = atan2f(r1, r0);
    iou = (iou + 1.f) * 0.5f;
    iou = fminf(fmaxf(iou, 0.f), 1.f);
    const float RECT[3] = {0.68f, 0.71f, 0.65f};
    float r = RECT[cls];
    float score = powf(shm, 1.f - r) * powf(iou, r);
    score = (score > 0.1f) ? score : 0.f;

    dout[t*7+0] = xg;  dout[t*7+1] = yg;  dout[t*7+2] = cz;
    dout[t*7+3] = d0;  dout[t*7+4] = d1;  dout[t*7+5] = d2;
    dout[t*7+6] = heading;
    dout[3500 + t] = score;
    dout[4000 + t] = (float)cls;
}

// ---------------------------------------------------------------------------
extern "C" void kernel_launch(void* const* d_in, const int* in_sizes, int n_in,
                              void* d_out, int out_size, void* d_ws, size_t ws_size,
                              hipStream_t stream)
{
    const float* x    = (const float*)d_in[0];   // [256][376][376]
    const float* W_sh = (const float*)d_in[1];   // [64][256][9]
    const float* bn_sh= (const float*)d_in[2];   // [4][64]
    const float* W1s  = (const float*)d_in[3];   // [6][64][64][9]
    const float* bn1s = (const float*)d_in[4];   // [6][4][64]
    const float* W2s  = (const float*)d_in[5];   // [6][3][64][9]
    const float* b2s  = (const float*)d_in[6];   // [6][3]
    float* dout = (float*)d_out;

    char* ws = (char*)d_ws;
    const size_t SHARED_B = (size_t)64*HWSZ*4;            // 36,192,256
    const size_t OFF_SHARED = 0;
    const size_t OFF_H1     = OFF_SHARED + SHARED_B;
    const size_t OFF_OUTS   = OFF_H1     + SHARED_B;      // 3 hm planes
    const size_t OFF_HIST   = OFF_OUTS   + (size_t)3*HWSZ*4;
    const size_t OFF_META   = OFF_HIST   + (size_t)NBIN*4;
    const size_t OFF_SORTED = OFF_META   + 256;
    const size_t OFF_G      = OFF_SORTED + (size_t)KTOP*8;
    const size_t OFF_CAND   = OFF_G      + (size_t)KTOP*9*4 + 64;
    const size_t OFF_RWSH   = OFF_CAND   + (size_t)CAND_CAP*8;
    const size_t OFF_RWBR   = OFF_RWSH   + (size_t)196608*4;
    const size_t OFF_RWHD   = OFF_RWBR   + (size_t)294912*4;

    float* f_shared = (float*)(ws + OFF_SHARED);
    float* f_h1     = (float*)(ws + OFF_H1);
    float* f_outs   = (float*)(ws + OFF_OUTS);
    unsigned* hist  = (unsigned*)(ws + OFF_HIST);
    unsigned* meta  = (unsigned*)(ws + OFF_META);
    unsigned long long* sorted = (unsigned long long*)(ws + OFF_SORTED);
    float* gbuf     = (float*)(ws + OFF_G);
    unsigned long long* cand = (unsigned long long*)(ws + OFF_CAND);
    float* rwsh = (float*)(ws + OFF_RWSH);
    float* rwbr = (float*)(ws + OFF_RWBR);
    float* rwhd = (float*)(ws + OFF_RWHD);

    dim3 blk(256);

    hipMemsetAsync(hist, 0, (size_t)NBIN*4, stream);

    // ---- weight reorders ----
    reorder_w12_kernel<<<(196608+255)/256, blk, 0, stream>>>(W_sh, rwsh, 256, 196608);
    reorder_w12_kernel<<<(294912+255)/256, blk, 0, stream>>>(W1s,  rwbr,  64, 294912);
    reorder_wh_kernel<<<(10368+255)/256,  blk, 0, stream>>>(W2s, rwhd, 10368);

    // ---- hm chain (bit-exact fp32) ----
    convb_kernel<256><<<dim3(12,47,2), blk, 0, stream>>>(x, rwsh, bn_sh, f_shared);
    convb_kernel<64><<<dim3(12,47,2), blk, 0, stream>>>(f_shared, rwbr, bn1s, f_h1);
    head3_kernel<<<dim3(12,24,1), blk, 0, stream>>>(f_h1, rwhd, b2s, f_outs, hist);

    // ---- top-k ----
    scan_kernel<<<1, 1024, 0, stream>>>(hist, meta);
    dim3 gscan((NSC + 255)/256);
    collect_kernel<<<gscan, blk, 0, stream>>>(f_outs, meta, cand);
    topk_sort_kernel<<<1, 512, SORT_M*sizeof(unsigned long long), stream>>>(
        meta, cand, sorted);

    // ---- branches 1..5 evaluated only at the 500 selected pixels ----
    branchpx_kernel<<<dim3(KTOP, 5), blk, 0, stream>>>(
        sorted, f_shared, rwbr, rwhd, bn1s, b2s, gbuf);

    // ---- assemble outputs ----
    finish_kernel<<<(KTOP+255)/256, blk, 0, stream>>>(sorted, gbuf, dout);

    (void)in_sizes; (void)n_in; (void)out_size; (void)ws_size;
}